// Round 9
// baseline (4633.757 us; speedup 1.0000x reference)
//
#include <hip/hip_runtime.h>
#include <hip/hip_bf16.h>

typedef __hip_bfloat16 bf16;
typedef short bf16x8 __attribute__((ext_vector_type(8)));
typedef float f32x4 __attribute__((ext_vector_type(4)));

#define DEV __device__ __forceinline__

DEV float bf2f(bf16 v) { return __bfloat162float(v); }
DEV bf16 f2bf(float v) { return __float2bfloat16(v); }
DEV unsigned short bfr(float f) {
  bf16 h = __float2bfloat16(f);
  return *reinterpret_cast<unsigned short*>(&h);
}
DEV float shf(unsigned short u) {
  unsigned int x = ((unsigned int)u) << 16;
  return *reinterpret_cast<float*>(&x);
}
DEV float gelu_exact(float x) { return 0.5f * x * (1.0f + erff(x * 0.70710678118654752f)); }

DEV float ldw(const void* p, long i, int isb) {
  return isb ? __bfloat162float(((const bf16*)p)[i]) : ((const float*)p)[i];
}

// ---------------- dtype detection + flag constants ----------------
__global__ void k_detect(const unsigned short* __restrict__ u, int* __restrict__ flag) {
  __shared__ int bad;
  if (threadIdx.x == 0) bad = 0;
  __syncthreads();
  for (int i = threadIdx.x; i < 8192; i += 256) {
    int expo = (u[i] >> 7) & 0xFF;
    if (expo >= 138) atomicOr(&bad, 1);
  }
  __syncthreads();
  if (threadIdx.x == 0) *flag = bad ? 0 : 1;
}
__global__ void k_zero2(int* a, int* b) { *a = 0; *b = 0; }

// ---------------- convert (bf16|fp32) -> fp32 ----------------
__global__ void k_cvt(const void* __restrict__ s, float* __restrict__ d, int n,
                      const int* __restrict__ fl) {
  int isb = *fl;
  int i = blockIdx.x * blockDim.x + threadIdx.x;
  if (i < n) d[i] = ldw(s, i, isb);
}

__global__ void k_zerosh(unsigned short* __restrict__ p, int n8) {
  int i = blockIdx.x * blockDim.x + threadIdx.x;
  if (i < n8) { uint4 z = {0, 0, 0, 0}; *(uint4*)(p + (long)i * 8) = z; }
}

// tokenizer weight [192][49] (at element offset 9408) -> bf16 [192][64] zero-padded
__global__ void k_padtokw(const void* __restrict__ tw, bf16* __restrict__ dst,
                          const int* __restrict__ fl) {
  int isb = *fl;
  int i = blockIdx.x * blockDim.x + threadIdx.x;
  if (i >= 12288) return;
  int n = i >> 6, k = i & 63;
  float v = (k < 49) ? ldw(tw, 9408 + (long)n * 49 + k, isb) : 0.0f;
  dst[i] = f2bf(v);
}

// conv weight pack: dst[s][np][icp] bf16 from src [OC][ICT][9], channel remap feats|warp|flow|0
__global__ void k_packw(const void* __restrict__ src, bf16* __restrict__ dst,
                        int OC, int C, int ICT, int NP, int ICP, int n,
                        const int* __restrict__ fl) {
  int isb = *fl;
  int i = blockIdx.x * blockDim.x + threadIdx.x;
  if (i >= n) return;
  int s = i / (NP * ICP);
  int r = i - s * NP * ICP;
  int oc = r / ICP, icp = r - oc * ICP;
  float v = 0.0f;
  if (oc < OC) {
    int ic = -1;
    if (icp < C) ic = icp;
    else if (icp < 2 * C) ic = icp - C + C + 2;
    else if (icp < 2 * C + 2) ic = icp - 2 * C + C;
    if (ic >= 0 && ic < ICT) v = ldw(src, ((long)oc * ICT + ic) * 9 + s, isb);
  }
  dst[i] = f2bf(v);
}

// feats [F][C][HW] -> pixel-major bf16 [F][HW][C]; one thread per 8-channel group
__global__ void k_trans_feats(const void* __restrict__ in, bf16* __restrict__ Fp,
                              int F, int C, int HW, const int* __restrict__ fl) {
  int isb = *fl;
  int cpg = C >> 3;
  int n = F * HW * cpg;
  int i = blockIdx.x * blockDim.x + threadIdx.x;
  if (i >= n) return;
  int p = i % HW;
  int rem = i / HW;
  int c8 = rem % cpg;
  int f = rem / cpg;
  long base = (long)f * C * HW + (long)(c8 * 8) * HW + p;
  union { unsigned short u[8]; uint4 v; } pk;
#pragma unroll
  for (int j = 0; j < 8; ++j) pk.u[j] = bfr(ldw(in, base + (long)j * HW, isb));
  *(uint4*)((unsigned short*)Fp + ((long)f * HW + p) * C + c8 * 8) = pk.v;
}

// ---------------- decoder conv1: single-wave, barrier-free, spill-free ----------------
template <int C, int ICP, int NP, int WW, int LGW>
__global__ __launch_bounds__(64, 2) void k_conv1d(
    const bf16* __restrict__ Fp, const float* __restrict__ flow,
    const bf16* __restrict__ Wp, const float* __restrict__ bias,
    bf16* __restrict__ out) {
  constexpr int HH = WW, HW = WW * WW;
  constexpr int ACW = 18, APX = 54;
  constexpr int NK = ICP / 32;
  __shared__ unsigned short As[APX][40];
  __shared__ int pofs[APX];
  __shared__ int doff[APX][4];
  __shared__ float dwt[APX][4];
  __shared__ float ffl[APX][2];
  int ln = threadIdx.x;
  int quad = ln >> 4, l16 = ln & 15;
  int n0 = blockIdx.x * 16, m0 = blockIdx.y * 16, b = blockIdx.z;
  int py0 = m0 >> LGW, px0 = m0 & (WW - 1);
  const unsigned short* fcur = (const unsigned short*)Fp + (long)b * HW * C;
  const unsigned short* fnxt = (const unsigned short*)Fp + (long)(b + 1) * HW * C;
  const float* fl = flow + (long)b * 2 * HW;
  if (ln < APX) {
    int sr = ln / ACW, sc = ln - sr * ACW;
    int py = py0 + sr - 1, px = px0 + sc - 1;
    bool in = py >= 0 && py < HH && px >= 0 && px < WW;
    int p = in ? (py * WW + px) : 0;
    pofs[ln] = in ? p * C : -1;
    float fx = in ? fl[p] : 0.0f, fy = in ? fl[HW + p] : 0.0f;
    float x = fminf(fmaxf((float)px + fx, 0.0f), (float)(WW - 1));
    float y = fminf(fmaxf((float)py + fy, 0.0f), (float)(HH - 1));
    int x0 = (int)floorf(x), y0 = (int)floorf(y);
    int x1 = min(x0 + 1, WW - 1), y1 = min(y0 + 1, HH - 1);
    float wx = x - (float)x0, wy = y - (float)y0;
    dwt[ln][0] = in ? (1 - wx) * (1 - wy) : 0.0f;
    dwt[ln][1] = in ? wx * (1 - wy) : 0.0f;
    dwt[ln][2] = in ? (1 - wx) * wy : 0.0f;
    dwt[ln][3] = in ? wx * wy : 0.0f;
    doff[ln][0] = (y0 * WW + x0) * C; doff[ln][1] = (y0 * WW + x1) * C;
    doff[ln][2] = (y1 * WW + x0) * C; doff[ln][3] = (y1 * WW + x1) * C;
    ffl[ln][0] = in ? fx : 0.0f; ffl[ln][1] = in ? fy : 0.0f;
  }
  const unsigned short* wrow = (const unsigned short*)Wp + (long)(n0 + l16) * ICP + quad * 8;
  f32x4 ac0 = {}, ac1 = {}, ac2 = {};
  for (int kc = 0; kc < NK; ++kc) {
    int chb = kc * 32;
    if (chb < C) {
      uint4 arg[4];
#pragma unroll
      for (int j = 0; j < 4; ++j) {
        int idx = ln + j * 64;
        if (idx < APX * 4) {
          int ap = idx >> 2, c4 = idx & 3;
          int po = pofs[ap];
          uint4 z = {0, 0, 0, 0};
          arg[j] = (po >= 0) ? *(const uint4*)(fcur + po + chb + c4 * 8) : z;
        }
      }
#pragma unroll
      for (int j = 0; j < 4; ++j) {
        int idx = ln + j * 64;
        if (idx < APX * 4) {
          int ap = idx >> 2, c4 = idx & 3;
          *(uint4*)&As[ap][c4 * 8] = arg[j];
        }
      }
    } else if (chb < 2 * C) {
#pragma unroll
      for (int j = 0; j < 4; ++j) {
        int idx = ln + j * 64;
        if (idx < APX * 4) {
          int ap = idx >> 2, c4 = idx & 3;
          int c = chb - C + c4 * 8;
          uint4 v0 = *(const uint4*)(fnxt + doff[ap][0] + c);
          uint4 v1 = *(const uint4*)(fnxt + doff[ap][1] + c);
          uint4 v2 = *(const uint4*)(fnxt + doff[ap][2] + c);
          uint4 v3 = *(const uint4*)(fnxt + doff[ap][3] + c);
          float q0 = dwt[ap][0], q1 = dwt[ap][1], q2 = dwt[ap][2], q3 = dwt[ap][3];
          union { unsigned short u[8]; uint4 v; } a0 = {.v = v0}, a1 = {.v = v1},
                                                  a2 = {.v = v2}, a3 = {.v = v3}, o;
#pragma unroll
          for (int e = 0; e < 8; ++e)
            o.u[e] = bfr(shf(a0.u[e]) * q0 + shf(a1.u[e]) * q1 +
                         shf(a2.u[e]) * q2 + shf(a3.u[e]) * q3);
          *(uint4*)&As[ap][c4 * 8] = o.v;
        }
      }
    } else {
#pragma unroll
      for (int j = 0; j < 4; ++j) {
        int idx = ln + j * 64;
        if (idx < APX * 4) {
          int ap = idx >> 2, c4 = idx & 3;
          union { unsigned short u[8]; uint4 v; } o = { .v = {0, 0, 0, 0} };
          if (c4 == 0) { o.u[0] = bfr(ffl[ap][0]); o.u[1] = bfr(ffl[ap][1]); }
          *(uint4*)&As[ap][c4 * 8] = o.v;
        }
      }
    }
#pragma unroll
    for (int s = 0; s < 9; ++s) {
      int ky = s / 3, kx = s - ky * 3;
      bf16x8 af = *(const bf16x8*)&As[ky * ACW + l16 + kx][quad * 8];
      bf16x8 wf = *(const bf16x8*)(wrow + (long)s * NP * ICP + chb);
      if (s % 3 == 0)      ac0 = __builtin_amdgcn_mfma_f32_16x16x32_bf16(af, wf, ac0, 0, 0, 0);
      else if (s % 3 == 1) ac1 = __builtin_amdgcn_mfma_f32_16x16x32_bf16(af, wf, ac1, 0, 0, 0);
      else                 ac2 = __builtin_amdgcn_mfma_f32_16x16x32_bf16(af, wf, ac2, 0, 0, 0);
    }
  }
  int n = n0 + l16;
  float bv = bias[n];
  long rowbase = (long)b * (HH + 2) * (WW + 2) + (long)(py0 + 1) * (WW + 2);
#pragma unroll
  for (int r = 0; r < 4; ++r) {
    int px = px0 + quad * 4 + r;
    float v = gelu_exact(ac0[r] + ac1[r] + ac2[r] + bv);
    ((unsigned short*)out)[(rowbase + px + 1) * NP + n] = bfr(v);
  }
}

// ---------------- decoder conv2: wave-per-pixel dual dot (N=2, K=9*C) ----------------
template <int C, int WW, int LGW>
__global__ __launch_bounds__(256) void k_conv2_dot(
    const bf16* __restrict__ mid, const bf16* __restrict__ Wq,
    const float* __restrict__ bias, float* __restrict__ cur) {
  constexpr int HH = WW;
  constexpr int HW = HH * WW;
  constexpr int Wp2 = WW + 2;
  constexpr int CPL = C / 64;  // channels per lane (2 or 1)
  int tid = threadIdx.x, wv = tid >> 6, ln = tid & 63;
  int gw = blockIdx.x * 4 + wv;
  int b = gw >> (2 * LGW);
  int p = gw & (HW - 1);
  int py = p >> LGW, px = p & (WW - 1);
  float r0 = cur[((long)b * 2 + 0) * HW + p];
  float r1 = cur[((long)b * 2 + 1) * HW + p];
  float b0 = bias[0], b1 = bias[1];
  const unsigned short* base = (const unsigned short*)mid +
      ((long)b * (HH + 2) * Wp2 + (long)py * Wp2 + px) * C + ln * CPL;
  const unsigned short* wb = (const unsigned short*)Wq + ln * CPL;
  float s0 = 0.0f, s1 = 0.0f;
#pragma unroll
  for (int t = 0; t < 9; ++t) {
    int dy = t / 3, dx = t - dy * 3;
    const unsigned short* ar = base + ((long)dy * Wp2 + dx) * C;
    const unsigned short* w0r = wb + (long)(t * 16 + 0) * C;
    const unsigned short* w1r = wb + (long)(t * 16 + 1) * C;
    if (CPL == 2) {
      unsigned int a = *(const unsigned int*)ar;
      unsigned int q0 = *(const unsigned int*)w0r;
      unsigned int q1 = *(const unsigned int*)w1r;
      float a0 = shf((unsigned short)a), a1 = shf((unsigned short)(a >> 16));
      s0 += a0 * shf((unsigned short)q0) + a1 * shf((unsigned short)(q0 >> 16));
      s1 += a0 * shf((unsigned short)q1) + a1 * shf((unsigned short)(q1 >> 16));
    } else {
      float a0 = shf(ar[0]);
      s0 += a0 * shf(w0r[0]);
      s1 += a0 * shf(w1r[0]);
    }
  }
#pragma unroll
  for (int o = 32; o; o >>= 1) { s0 += __shfl_xor(s0, o); s1 += __shfl_xor(s1, o); }
  if (ln == 0) {
    cur[((long)b * 2 + 0) * HW + p] = s0 + b0 + r0;
    cur[((long)b * 2 + 1) * HW + p] = s1 + b1 + r1;
  }
}

// ---------------- local correlation from pixel-major bf16 Fp2, bf16 out, stride 64 -------
__global__ void k_corr(const bf16* __restrict__ Fp2, bf16* __restrict__ corrT) {
  __shared__ unsigned short f1r[128];
  int p = blockIdx.x;
  int b = blockIdx.y;
  int t = threadIdx.x;  // 64
  const unsigned short* f1 = (const unsigned short*)Fp2 + ((long)b * 1024 + p) * 128;
  if (t < 16) *(uint4*)&f1r[t * 8] = *(const uint4*)(f1 + t * 8);
  __syncthreads();
  long rowo = ((long)b * 1024 + p) * 64;
  if (t < 49) {
    int dy = t / 7 - 3, dx = t % 7 - 3;
    int h = p >> 5, w = p & 31;
    int p2 = (((h - dy) & 31) << 5) | ((w - dx) & 31);
    const unsigned short* f2 = (const unsigned short*)Fp2 + ((long)(b + 1) * 1024 + p2) * 128;
    float s = 0.0f;
    for (int c = 0; c < 128; c += 8) {
      union { unsigned short u[8]; uint4 v; } av = { .v = *(const uint4*)&f1r[c] };
      union { unsigned short u[8]; uint4 v; } bv = { .v = *(const uint4*)(f2 + c) };
#pragma unroll
      for (int j = 0; j < 8; ++j) s += shf(av.u[j]) * shf(bv.u[j]);
    }
    corrT[rowo + t] = f2bf(s * 0.08838834764831845f);
  } else {
    corrT[rowo + t] = f2bf(0.0f);
  }
}

// ================= persistent transformer megakernel =================
// 256 blocks x 256 threads (1 block/CU -> co-residency guaranteed). Software grid
// barrier: arrivals via contended fetch_add on its own cacheline; waiters poll the
// generation counter with RELAXED/ACQUIRE atomic LOADS (no RMW) + s_sleep backoff.

DEV void gridbar(int* cnt, int* gen) {
  __threadfence();
  __syncthreads();
  if (threadIdx.x == 0) {
    int g = __hip_atomic_load(gen, __ATOMIC_RELAXED, __HIP_MEMORY_SCOPE_AGENT);
    int a = __hip_atomic_fetch_add(cnt, 1, __ATOMIC_ACQ_REL, __HIP_MEMORY_SCOPE_AGENT);
    if (a == 255) {
      __hip_atomic_store(cnt, 0, __ATOMIC_RELAXED, __HIP_MEMORY_SCOPE_AGENT);
      __hip_atomic_fetch_add(gen, 1, __ATOMIC_ACQ_REL, __HIP_MEMORY_SCOPE_AGENT);
    } else {
      while (__hip_atomic_load(gen, __ATOMIC_ACQUIRE, __HIP_MEMORY_SCOPE_AGENT) == g)
        __builtin_amdgcn_s_sleep(16);
    }
  }
  __syncthreads();
  __threadfence();
}

// wave-level GEMM phase: 16 rows x 64 cols per tile, tiles strided over 1024 waves.
// AMODE: 0 fp32 A; 1 bf16 A; 2 fused attention merge; 3 fused LayerNorm.
template <int KT, int ACT, bool HASRES, int AMODE, int OUTBF, int VT>
DEV void gemm_ph(unsigned short* wls, int gw, int ln,
                 const void* A, const void* W, long woff,
                 const void* bias, long boff, int isbb,
                 const float* res, void* C, int N, int isb,
                 const unsigned short* mop, const float* mml, bf16* vtout,
                 const void* lnw, long lnwoff, const void* lnb, long lnboff) {
  constexpr int NK = KT / 32;
  int quad = ln >> 4, l16 = ln & 15;
  int ntn = N >> 6;
  int ntiles = 128 * ntn;
  for (int t = gw; t < ntiles; t += 1024) {
    int tn = t % ntn, tm = t / ntn;
    int m0 = tm * 16, n0 = tn * 64;
    if constexpr (AMODE == 3) {
      int row = ln >> 2, j = ln & 3;
      const float* xr = (const float*)A + (long)(m0 + row) * 192 + j * 48;
      float av[48];
#pragma unroll
      for (int q = 0; q < 12; ++q) {
        float4 v = *(const float4*)(xr + q * 4);
        av[q * 4 + 0] = v.x; av[q * 4 + 1] = v.y;
        av[q * 4 + 2] = v.z; av[q * 4 + 3] = v.w;
      }
      float sum = 0.0f;
#pragma unroll
      for (int q = 0; q < 48; ++q) sum += av[q];
      sum += __shfl_xor(sum, 1);
      sum += __shfl_xor(sum, 2);
      float mean = sum * (1.0f / 192.0f);
      float vs = 0.0f;
#pragma unroll
      for (int q = 0; q < 48; ++q) { float d = av[q] - mean; vs += d * d; }
      vs += __shfl_xor(vs, 1);
      vs += __shfl_xor(vs, 2);
      float rstd = rsqrtf(vs * (1.0f / 192.0f) + 1e-5f);
#pragma unroll
      for (int g = 0; g < 6; ++g) {
        union { unsigned short u[8]; uint4 v; } pk;
#pragma unroll
        for (int e = 0; e < 8; ++e) {
          long k = j * 48 + g * 8 + e;
          float gg = ldw(lnw, lnwoff + k, isb);
          float bb = ldw(lnb, lnboff + k, isb);
          pk.u[e] = bfr((av[g * 8 + e] - mean) * rstd * gg + bb);
        }
        *(uint4*)&wls[row * 200 + j * 48 + g * 8] = pk.v;
      }
    } else if constexpr (AMODE == 2) {
      int row = ln >> 2, j = ln & 3;
      int m = m0 + row;
      int rr = m & 1023, bb = m >> 10;
      long idx[4];
      float ms[4], ls[4];
      float Ms = -1e30f;
#pragma unroll
      for (int s = 0; s < 4; ++s) {
        idx[s] = (((long)s * 2 + bb) * 4 + j) * 1024 + rr;
        ms[s] = mml[idx[s] * 2];
        ls[s] = mml[idx[s] * 2 + 1];
        Ms = fmaxf(Ms, ms[s]);
      }
      float e4[4], L = 0.0f;
#pragma unroll
      for (int s = 0; s < 4; ++s) { e4[s] = __expf(ms[s] - Ms); L += ls[s] * e4[s]; }
      float invL = 1.0f / L;
#pragma unroll
      for (int g = 0; g < 6; ++g) {
        union { unsigned short u[8]; uint4 v; } pk;
#pragma unroll
        for (int e2 = 0; e2 < 8; ++e2) {
          float o = 0.0f;
#pragma unroll
          for (int s = 0; s < 4; ++s) o += shf(mop[idx[s] * 48 + g * 8 + e2]) * e4[s];
          pk.u[e2] = bfr(o * invL);
        }
        *(uint4*)&wls[row * 200 + j * 48 + g * 8] = pk.v;
      }
    }
    f32x4 acc[4] = {};
    auto lda = [&](int kc) -> bf16x8 {
      if constexpr (AMODE >= 2) {
        return *(const bf16x8*)&wls[l16 * 200 + kc * 32 + quad * 8];
      } else if constexpr (AMODE == 1) {
        return *(const bf16x8*)((const unsigned short*)A + (long)(m0 + l16) * KT + kc * 32 + quad * 8);
      } else {
        const float* ap = (const float*)A + (long)(m0 + l16) * KT + kc * 32 + quad * 8;
        float4 a0 = *(const float4*)ap;
        float4 a1 = *(const float4*)(ap + 4);
        union { unsigned short u[8]; bf16x8 v; } pk;
        pk.u[0] = bfr(a0.x); pk.u[1] = bfr(a0.y); pk.u[2] = bfr(a0.z); pk.u[3] = bfr(a0.w);
        pk.u[4] = bfr(a1.x); pk.u[5] = bfr(a1.y); pk.u[6] = bfr(a1.z); pk.u[7] = bfr(a1.w);
        return pk.v;
      }
    };
    if (isb) {
      const unsigned short* wb = (const unsigned short*)W + woff + (long)l16 * KT + quad * 8;
      for (int kc = 0; kc < NK; ++kc) {
        bf16x8 af = lda(kc);
#pragma unroll
        for (int nt = 0; nt < 4; ++nt) {
          bf16x8 wf = *(const bf16x8*)(wb + (long)(n0 + nt * 16) * KT + kc * 32);
          acc[nt] = __builtin_amdgcn_mfma_f32_16x16x32_bf16(af, wf, acc[nt], 0, 0, 0);
        }
      }
    } else {
      const float* wb = (const float*)W + woff + (long)l16 * KT + quad * 8;
      for (int kc = 0; kc < NK; ++kc) {
        bf16x8 af = lda(kc);
#pragma unroll
        for (int nt = 0; nt < 4; ++nt) {
          const float* wp = wb + (long)(n0 + nt * 16) * KT + kc * 32;
          float4 w0 = *(const float4*)wp;
          float4 w1 = *(const float4*)(wp + 4);
          union { unsigned short u[8]; bf16x8 v; } pk;
          pk.u[0] = bfr(w0.x); pk.u[1] = bfr(w0.y); pk.u[2] = bfr(w0.z); pk.u[3] = bfr(w0.w);
          pk.u[4] = bfr(w1.x); pk.u[5] = bfr(w1.y); pk.u[6] = bfr(w1.z); pk.u[7] = bfr(w1.w);
          acc[nt] = __builtin_amdgcn_mfma_f32_16x16x32_bf16(af, pk.v, acc[nt], 0, 0, 0);
        }
      }
    }
#pragma unroll
    for (int nt = 0; nt < 4; ++nt) {
      int n = n0 + nt * 16 + l16;
      float bv = ldw(bias, boff + n, isbb);
#pragma unroll
      for (int r = 0; r < 4; ++r) {
        int m = m0 + quad * 4 + r;
        float v = acc[nt][r] + bv;
        if (HASRES) v += res[(long)m * N + n];
        if (ACT == 1) v = gelu_exact(v);
        if (OUTBF) ((bf16*)C)[(long)m * N + n] = f2bf(v);
        else ((float*)C)[(long)m * N + n] = v;
        if constexpr (VT) {
          if (n >= 384) {
            int hh = (n - 384) / 48, dd = (n - 384) % 48;
            int row = m & 1023, bb = m >> 10;
            vtout[((long)(bb * 4 + hh) * 48 + dd) * 1024 + row] = f2bf(v);
          }
        }
      }
    }
  }
}

// attention phase: 512 units strided over 256 blocks (exactly 2 each)
DEV void attn_ph(unsigned short* SM, int bid, int tid,
                 const bf16* qkv, const bf16* vt,
                 unsigned short* opart, float* ml) {
  unsigned short* Qs = SM;              // [64][72]
  unsigned short* Ks = SM + 64 * 72;    // [64][72]
  unsigned short* Vs = SM + 128 * 72;   // [48][72]
  unsigned short* Ps = SM + 176 * 72;   // [64][72]
  int wv = tid >> 6, ln = tid & 63, quad = ln >> 4, l16 = ln & 15;
  const float SC = 0.14433756729740643f;
  for (int u = bid; u < 512; u += 256) {
    int bx = u & 63;
    int h = (u >> 6) & 3, b = u >> 8;
    int qt = bx >> 2, s = bx & 3;
    int q0 = qt * 64;
    const unsigned short* qp = (const unsigned short*)qkv + (long)b * 1024 * 576;
    const unsigned short* vp = (const unsigned short*)vt + ((long)(b * 4 + h) * 48) * 1024;
    for (int i = tid; i < 384; i += 256) {
      int r = i / 6, c = i % 6;
      *(uint4*)&Qs[r * 72 + c * 8] = *(const uint4*)(qp + (long)(q0 + r) * 576 + h * 48 + c * 8);
    }
    for (int i = tid; i < 128; i += 256) {
      int r = i >> 1, c = 6 + (i & 1);
      uint4 z = {0, 0, 0, 0};
      *(uint4*)&Qs[r * 72 + c * 8] = z;
    }
    float m[4] = {-1e30f, -1e30f, -1e30f, -1e30f};
    float l[4] = {0.0f, 0.0f, 0.0f, 0.0f};
    f32x4 accO[3] = {};
    for (int kc = s * 4; kc < s * 4 + 4; ++kc) {
      int k0 = kc * 64;
      for (int i = tid; i < 384; i += 256) {
        int r = i / 6, c = i % 6;
        *(uint4*)&Ks[r * 72 + c * 8] =
            *(const uint4*)(qp + (long)(k0 + r) * 576 + 192 + h * 48 + c * 8);
      }
      for (int i = tid; i < 128; i += 256) {
        int r = i >> 1, c = 6 + (i & 1);
        uint4 z = {0, 0, 0, 0};
        *(uint4*)&Ks[r * 72 + c * 8] = z;
      }
      for (int i = tid; i < 384; i += 256) {
        int d = i >> 3, c = i & 7;
        *(uint4*)&Vs[d * 72 + c * 8] = *(const uint4*)(vp + (long)d * 1024 + k0 + c * 8);
      }
      __syncthreads();
      f32x4 accS[4] = {};
      bf16x8 a0 = *(const bf16x8*)&Qs[(wv * 16 + l16) * 72 + quad * 8];
      bf16x8 a1 = *(const bf16x8*)&Qs[(wv * 16 + l16) * 72 + 32 + quad * 8];
#pragma unroll
      for (int ct = 0; ct < 4; ++ct) {
        bf16x8 b0 = *(const bf16x8*)&Ks[(ct * 16 + l16) * 72 + quad * 8];
        bf16x8 b1 = *(const bf16x8*)&Ks[(ct * 16 + l16) * 72 + 32 + quad * 8];
        accS[ct] = __builtin_amdgcn_mfma_f32_16x16x32_bf16(a0, b0, accS[ct], 0, 0, 0);
        accS[ct] = __builtin_amdgcn_mfma_f32_16x16x32_bf16(a1, b1, accS[ct], 0, 0, 0);
      }
#pragma unroll
      for (int r = 0; r < 4; ++r) {
        float s0 = accS[0][r] * SC, s1 = accS[1][r] * SC;
        float s2 = accS[2][r] * SC, s3 = accS[3][r] * SC;
        float mx = fmaxf(fmaxf(s0, s1), fmaxf(s2, s3));
        for (int o = 8; o; o >>= 1) mx = fmaxf(mx, __shfl_xor(mx, o));
        float mn = fmaxf(m[r], mx);
        float alpha = __expf(m[r] - mn);
        float p0 = __expf(s0 - mn), p1 = __expf(s1 - mn);
        float p2 = __expf(s2 - mn), p3 = __expf(s3 - mn);
        float rs = p0 + p1 + p2 + p3;
        for (int o = 8; o; o >>= 1) rs += __shfl_xor(rs, o);
        m[r] = mn;
        l[r] = l[r] * alpha + rs;
        accO[0][r] *= alpha; accO[1][r] *= alpha; accO[2][r] *= alpha;
        int prow = wv * 16 + quad * 4 + r;
        Ps[prow * 72 + l16]      = bfr(p0);
        Ps[prow * 72 + 16 + l16] = bfr(p1);
        Ps[prow * 72 + 32 + l16] = bfr(p2);
        Ps[prow * 72 + 48 + l16] = bfr(p3);
      }
      bf16x8 pf0 = *(const bf16x8*)&Ps[(wv * 16 + l16) * 72 + quad * 8];
      bf16x8 pf1 = *(const bf16x8*)&Ps[(wv * 16 + l16) * 72 + 32 + quad * 8];
#pragma unroll
      for (int ct = 0; ct < 3; ++ct) {
        bf16x8 v0 = *(const bf16x8*)&Vs[(ct * 16 + l16) * 72 + quad * 8];
        bf16x8 v1 = *(const bf16x8*)&Vs[(ct * 16 + l16) * 72 + 32 + quad * 8];
        accO[ct] = __builtin_amdgcn_mfma_f32_16x16x32_bf16(pf0, v0, accO[ct], 0, 0, 0);
        accO[ct] = __builtin_amdgcn_mfma_f32_16x16x32_bf16(pf1, v1, accO[ct], 0, 0, 0);
      }
      __syncthreads();
    }
    long base = (((long)s * 2 + b) * 4 + h) * 1024;
#pragma unroll
    for (int r = 0; r < 4; ++r) {
      int row = q0 + wv * 16 + quad * 4 + r;
#pragma unroll
      for (int ct = 0; ct < 3; ++ct)
        opart[(base + row) * 48 + ct * 16 + l16] = bfr(accO[ct][r]);
      if (l16 == 0) {
        ml[(base + row) * 2]     = m[r];
        ml[(base + row) * 2 + 1] = l[r];
      }
    }
  }
}

__global__ __launch_bounds__(256, 2) void k_mega(
    const int* flag, int* barcnt, int* bargen,
    float* x, const bf16* corrTb, const bf16* wtok, const void* tok_b,
    bf16* qkvbb, bf16* vtb, unsigned short* opart, float* mlbuf,
    bf16* hidb, float* headh, float* cur,
    const void* lcm_ln1_w, const void* lcm_ln1_b, const void* lcm_in_w, const void* lcm_in_b,
    const void* lcm_out_w, const void* lcm_out_b, const void* lcm_ln2_w, const void* lcm_ln2_b,
    const void* lcm_mlp_w1, const void* lcm_mlp_b1, const void* lcm_mlp_w2, const void* lcm_mlp_b2,
    const void* gtr_ln1_w, const void* gtr_ln1_b, const void* gtr_in_w, const void* gtr_in_b,
    const void* gtr_out_w, const void* gtr_out_b, const void* gtr_ln2_w, const void* gtr_ln2_b,
    const void* gtr_mlp_w1, const void* gtr_mlp_b1, const void* gtr_mlp_w2, const void* gtr_mlp_b2,
    const void* head_w1, const void* head_b1, const void* head_w2, const void* head_b2) {
  __shared__ unsigned short SM[17280];  // attn: 240x72 | gemm: 4 waves x 16x200
  int tid = threadIdx.x, bid = blockIdx.x;
  int wv = tid >> 6, ln = tid & 63;
  int gw = bid * 4 + wv;
  unsigned short* wls = SM + wv * 3200;
  int isb = *flag;
  // phase 0: tokenizer GEMM (A/W packed bf16, bias raw)
  gemm_ph<64, 0, false, 1, 0, 0>(wls, gw, ln, corrTb, wtok, 0, tok_b, 192, isb,
                                 nullptr, x, 192, 1, nullptr, nullptr, nullptr,
                                 nullptr, 0, nullptr, 0);
  gridbar(barcnt, bargen);
  for (int blk = 0; blk < 8; ++blk) {
    long i = (blk < 6) ? blk : (blk - 6);
    const void *ln1w, *ln1b, *inw, *inb, *ow, *ob, *ln2w, *ln2b, *w1, *b1, *w2, *b2;
    if (blk < 6) {
      ln1w = lcm_ln1_w; ln1b = lcm_ln1_b; inw = lcm_in_w; inb = lcm_in_b;
      ow = lcm_out_w; ob = lcm_out_b; ln2w = lcm_ln2_w; ln2b = lcm_ln2_b;
      w1 = lcm_mlp_w1; b1 = lcm_mlp_b1; w2 = lcm_mlp_w2; b2 = lcm_mlp_b2;
    } else {
      ln1w = gtr_ln1_w; ln1b = gtr_ln1_b; inw = gtr_in_w; inb = gtr_in_b;
      ow = gtr_out_w; ob = gtr_out_b; ln2w = gtr_ln2_w; ln2b = gtr_ln2_b;
      w1 = gtr_mlp_w1; b1 = gtr_mlp_b1; w2 = gtr_mlp_w2; b2 = gtr_mlp_b2;
    }
    long o1 = i * 192, o2 = i * 192, o3 = i * 110592, o4 = i * 576;
    long o5 = i * 36864, o6 = i * 192, o7 = i * 192, o8 = i * 192;
    long o9 = i * 147456, o10 = i * 768, o11 = i * 147456, o12 = i * 192;
    // LN1 + qkv (+V-transpose scatter)
    gemm_ph<192, 0, false, 3, 1, 1>(wls, gw, ln, x, inw, o3, inb, o4, isb,
                                    nullptr, qkvbb, 576, isb, nullptr, nullptr, vtb,
                                    ln1w, o1, ln1b, o2);
    gridbar(barcnt, bargen);
    attn_ph(SM, bid, tid, qkvbb, vtb, opart, mlbuf);
    gridbar(barcnt, bargen);
    // merge + out-proj (+residual, in-place x)
    gemm_ph<192, 0, true, 2, 0, 0>(wls, gw, ln, nullptr, ow, o5, ob, o6, isb,
                                   x, x, 192, isb, opart, mlbuf, nullptr,
                                   nullptr, 0, nullptr, 0);
    gridbar(barcnt, bargen);
    // LN2 + mlp1 (gelu)
    gemm_ph<192, 1, false, 3, 1, 0>(wls, gw, ln, x, w1, o9, b1, o10, isb,
                                    nullptr, hidb, 768, isb, nullptr, nullptr, nullptr,
                                    ln2w, o7, ln2b, o8);
    gridbar(barcnt, bargen);
    // mlp2 (+residual, in-place x)
    gemm_ph<768, 0, true, 1, 0, 0>(wls, gw, ln, hidb, w2, o11, b2, o12, isb,
                                   x, x, 192, isb, nullptr, nullptr, nullptr,
                                   nullptr, 0, nullptr, 0);
    gridbar(barcnt, bargen);
    if (blk == 5) {
      int gt = bid * 256 + tid;
      for (int e = gt; e < 196608; e += 65536)
        x[196608 + e] = 0.8f * x[196608 + e] + 0.2f * x[e];
      gridbar(barcnt, bargen);
    }
  }
  // head layer 1 (gelu, fp32 out)
  gemm_ph<192, 1, false, 0, 0, 0>(wls, gw, ln, x, head_w1, 0, head_b1, 0, isb,
                                  nullptr, headh, 192, isb, nullptr, nullptr, nullptr,
                                  nullptr, 0, nullptr, 0);
  gridbar(barcnt, bargen);
  // head layer 2: wave-per-output dot, writes cur [b][2][1024]
  for (int t2 = gw; t2 < 4096; t2 += 1024) {
    int m = t2 >> 1, n = t2 & 1;
    const float* a = headh + (long)m * 192;
    float s = 0.0f;
#pragma unroll
    for (int q = 0; q < 3; ++q) {
      int j = ln + q * 64;
      s += a[j] * ldw(head_w2, (long)n * 192 + j, isb);
    }
    for (int o = 32; o; o >>= 1) s += __shfl_xor(s, o);
    if (ln == 0) {
      int b = m >> 10, p = m & 1023;
      cur[((long)b * 2 + n) * 1024 + p] = s + ldw(head_b2, n, isb);
    }
  }
}

// ---------------- upsample / out ----------------
__global__ void k_upsample(const float* __restrict__ in, float* __restrict__ out) {
  int i = blockIdx.x * blockDim.x + threadIdx.x;
  if (i >= 2 * 2 * 64 * 64) return;
  int p = i & 4095;
  int bc = i >> 12;
  int oy = p >> 6, ox = p & 63;
  float sx = ox * (31.0f / 63.0f), sy = oy * (31.0f / 63.0f);
  int x0 = (int)sx, y0 = (int)sy;
  int x1 = min(x0 + 1, 31), y1 = min(y0 + 1, 31);
  float wx = sx - x0, wy = sy - y0;
  const float* ic = in + (long)bc * 1024;
  out[i] = ic[y0 * 32 + x0] * (1 - wx) * (1 - wy) + ic[y0 * 32 + x1] * wx * (1 - wy)
         + ic[y1 * 32 + x0] * (1 - wx) * wy      + ic[y1 * 32 + x1] * wx * wy;
}

__global__ void k_out(const float* __restrict__ cur2, void* __restrict__ out,
                      const int* __restrict__ fl) {
  int isb = *fl;
  int i = blockIdx.x * blockDim.x + threadIdx.x;
  if (i < 16384) {
    if (isb) ((bf16*)out)[i] = f2bf(cur2[i]);
    else ((float*)out)[i] = cur2[i];
  }
}

extern "C" void kernel_launch(void* const* d_in, const int* in_sizes, int n_in,
                              void* d_out, int out_size, void* d_ws, size_t ws_size,
                              hipStream_t stream) {
  const void* feats_l1 = d_in[0];
  const void* feats_l2 = d_in[1];
  const void* tok_w = d_in[3];
  const void* tok_b = d_in[4];
  const void* lcm_ln1_w = d_in[5];
  const void* lcm_ln1_b = d_in[6];
  const void* lcm_in_w  = d_in[7];
  const void* lcm_in_b  = d_in[8];
  const void* lcm_out_w = d_in[9];
  const void* lcm_out_b = d_in[10];
  const void* lcm_ln2_w = d_in[11];
  const void* lcm_ln2_b = d_in[12];
  const void* lcm_mlp_w1 = d_in[13];
  const void* lcm_mlp_b1 = d_in[14];
  const void* lcm_mlp_w2 = d_in[15];
  const void* lcm_mlp_b2 = d_in[16];
  const void* gtr_ln1_w = d_in[17];
  const void* gtr_ln1_b = d_in[18];
  const void* gtr_in_w  = d_in[19];
  const void* gtr_in_b  = d_in[20];
  const void* gtr_out_w = d_in[21];
  const void* gtr_out_b = d_in[22];
  const void* gtr_ln2_w = d_in[23];
  const void* gtr_ln2_b = d_in[24];
  const void* gtr_mlp_w1 = d_in[25];
  const void* gtr_mlp_b1 = d_in[26];
  const void* gtr_mlp_w2 = d_in[27];
  const void* gtr_mlp_b2 = d_in[28];
  const void* head_w1 = d_in[29];
  const void* head_b1 = d_in[30];
  const void* head_w2 = d_in[31];
  const void* head_b2 = d_in[32];
  const void* ref1_w1 = d_in[33];
  const void* ref1_b1 = d_in[34];
  const void* ref1_w2 = d_in[35];
  const void* ref1_b2 = d_in[36];
  const void* ref0_w1 = d_in[37];
  const void* ref0_b1 = d_in[38];
  const void* ref0_w2 = d_in[39];
  const void* ref0_b2 = d_in[40];
  (void)ws_size; (void)n_in; (void)in_sizes; (void)out_size;

  // ---- workspace layout (f-eq units; ~16.8 MB) ----
  int* flag = (int*)d_ws;
  int* barcnt = (int*)d_ws + 16;   // own cacheline (byte 64)
  int* bargen = (int*)d_ws + 64;   // own cacheline (byte 256) — inside spare F2
  float* wsf = (float*)d_ws;
  float* F2   = wsf + 16;             // 393216 (spare; holds barrier words only)
  float* rA   = F2 + 393216;          // 786432 : opart bf16
  float* rX   = rA + 786432;          // 393216 : residual x
  float* rT   = rX + 393216;          // 393216 : head-hidden | mid0packed
  float* rY   = rT + 393216;          // 393216 : mlbuf | mid1packed
  float* big  = rY + 393216;          // 1572864: qkv/vt/hid [0,851968) | Fp2+Fp1 tail
  float* fv   = big + 1572864;        // 4096 (unused)
  float* cur  = fv + 4096;            // 4096
  float* cur2 = cur + 4096;           // 16384
  float* cb1a = cur2 + 16384;         // 128
  float* cb1b = cb1a + 128;           // 16
  float* cb0a = cb1b + 16;            // 64
  float* cb0b = cb0a + 64;            // 16
  bf16* wtok  = (bf16*)(cb0b + 16);   // 12288 shorts
  float* wpk  = cb0b + 16 + 6144;
  bf16* w1p1 = (bf16*)wpk;            // 331776 shorts
  bf16* w1p2 = (bf16*)(wpk + 165888); // 18432 shorts
  bf16* w0p1 = (bf16*)(wpk + 175104); // 92160 shorts
  bf16* w0p2 = (bf16*)(wpk + 221184); // 9216 shorts

  float* x = rX;
  bf16* corrTb = (bf16*)big;
  bf16* qkvbb  = (bf16*)big;
  bf16* vtb    = (bf16*)(big + 655360);
  bf16* hidb   = (bf16*)big;
  unsigned short* opart = (unsigned short*)rA;  // [4][2][4][1024][48] bf16
  float* mlbuf = rY;                            // [4][2][4][1024][2] fp32
  float* headh = rT;
  bf16* mid0p = (bf16*)rT;
  bf16* mid1p = (bf16*)rY;
  bf16* Fp2   = (bf16*)(big + 851968);   // [3][1024][128] = 393216 shorts
  bf16* Fp1   = (bf16*)(big + 1048576);  // [3][4096][64]  = 786432 shorts

  k_detect<<<1, 256, 0, stream>>>((const unsigned short*)feats_l1, flag);
  k_zero2<<<1, 1, 0, stream>>>(barcnt, bargen);
  k_cvt<<<1, 256, 0, stream>>>(ref1_b1, cb1a, 128, flag);
  k_cvt<<<1, 256, 0, stream>>>(ref1_b2, cb1b, 2, flag);
  k_cvt<<<1, 256, 0, stream>>>(ref0_b1, cb0a, 64, flag);
  k_cvt<<<1, 256, 0, stream>>>(ref0_b2, cb0b, 2, flag);
  k_padtokw<<<48, 256, 0, stream>>>(tok_w, wtok, flag);
  k_packw<<<1296, 256, 0, stream>>>(ref1_w1, w1p1, 128, 128, 258, 128, 288, 331776, flag);
  k_packw<<<72, 256, 0, stream>>>(ref1_w2, w1p2, 2, 128, 128, 16, 128, 18432, flag);
  k_packw<<<360, 256, 0, stream>>>(ref0_w1, w0p1, 64, 64, 130, 64, 160, 92160, flag);
  k_packw<<<36, 256, 0, stream>>>(ref0_w2, w0p2, 2, 64, 64, 16, 64, 9216, flag);
  // pixel-major frames up front (big tail survives qkv/hid which use [0,851968))
  k_trans_feats<<<192, 256, 0, stream>>>(feats_l2, Fp2, 3, 128, 1024, flag);
  k_trans_feats<<<384, 256, 0, stream>>>(feats_l1, Fp1, 3, 64, 4096, flag);

  // ---- tokens: corr (from Fp2) ----
  k_corr<<<dim3(1024, 2), 64, 0, stream>>>(Fp2, corrTb);

  // ---- whole transformer + head as ONE persistent kernel (43 grid barriers) ----
  k_mega<<<256, 256, 0, stream>>>(
      flag, barcnt, bargen, x, corrTb, wtok, tok_b,
      qkvbb, vtb, opart, mlbuf, hidb, headh, cur,
      lcm_ln1_w, lcm_ln1_b, lcm_in_w, lcm_in_b, lcm_out_w, lcm_out_b,
      lcm_ln2_w, lcm_ln2_b, lcm_mlp_w1, lcm_mlp_b1, lcm_mlp_w2, lcm_mlp_b2,
      gtr_ln1_w, gtr_ln1_b, gtr_in_w, gtr_in_b, gtr_out_w, gtr_out_b,
      gtr_ln2_w, gtr_ln2_b, gtr_mlp_w1, gtr_mlp_b1, gtr_mlp_w2, gtr_mlp_b2,
      head_w1, head_b1, head_w2, head_b2);

  // ---- decoder prep: zero mid buffers (borders must stay 0) ----
  k_zerosh<<<768, 256, 0, stream>>>((unsigned short*)rT, 196608);

  // ---- decoder level 1 (32x32): C=128, ICP=288, OC=128 ----
  for (int it = 0; it < 4; ++it) {
    k_conv1d<128, 288, 128, 32, 5><<<dim3(8, 64, 2), 64, 0, stream>>>(
        Fp2, cur, w1p1, cb1a, mid1p);
    k_conv2_dot<128, 32, 5><<<512, 256, 0, stream>>>(mid1p, w1p2, cb1b, cur);
  }
  k_upsample<<<64, 256, 0, stream>>>(cur, cur2);

  // ---- decoder level 0 (64x64): C=64, ICP=160, OC=64 ----
  for (int it = 0; it < 4; ++it) {
    k_conv1d<64, 160, 64, 64, 6><<<dim3(4, 256, 2), 64, 0, stream>>>(
        Fp1, cur2, w0p1, cb0a, mid0p);
    k_conv2_dot<64, 64, 6><<<2048, 256, 0, stream>>>(mid0p, w0p2, cb0b, cur2);
  }

  k_out<<<64, 256, 0, stream>>>(cur2, d_out, flag);
}

// Round 10
// 1640.211 us; speedup vs baseline: 2.8251x; 2.8251x over previous
//
#include <hip/hip_runtime.h>
#include <hip/hip_bf16.h>

typedef __hip_bfloat16 bf16;
typedef short bf16x8 __attribute__((ext_vector_type(8)));
typedef float f32x4 __attribute__((ext_vector_type(4)));

#define DEV __device__ __forceinline__

DEV float bf2f(bf16 v) { return __bfloat162float(v); }
DEV bf16 f2bf(float v) { return __float2bfloat16(v); }
DEV unsigned short bfr(float f) {
  bf16 h = __float2bfloat16(f);
  return *reinterpret_cast<unsigned short*>(&h);
}
DEV float shf(unsigned short u) {
  unsigned int x = ((unsigned int)u) << 16;
  return *reinterpret_cast<float*>(&x);
}
DEV float gelu_exact(float x) { return 0.5f * x * (1.0f + erff(x * 0.70710678118654752f)); }

DEV float ldw(const void* p, long i, int isb) {
  return isb ? __bfloat162float(((const bf16*)p)[i]) : ((const float*)p)[i];
}

// ---------------- dtype detection + flag constants ----------------
__global__ void k_detect(const unsigned short* __restrict__ u, int* __restrict__ flag) {
  __shared__ int bad;
  if (threadIdx.x == 0) bad = 0;
  __syncthreads();
  for (int i = threadIdx.x; i < 8192; i += 256) {
    int expo = (u[i] >> 7) & 0xFF;
    if (expo >= 138) atomicOr(&bad, 1);
  }
  __syncthreads();
  if (threadIdx.x == 0) *flag = bad ? 0 : 1;
}
// zero the barrier state: gen + 256 per-block flag cachelines
__global__ void k_zerobar(int* gen, int* flags) {
  flags[threadIdx.x * 32] = 0;
  if (threadIdx.x == 0) *gen = 0;
}

// ---------------- convert (bf16|fp32) -> fp32 ----------------
__global__ void k_cvt(const void* __restrict__ s, float* __restrict__ d, int n,
                      const int* __restrict__ fl) {
  int isb = *fl;
  int i = blockIdx.x * blockDim.x + threadIdx.x;
  if (i < n) d[i] = ldw(s, i, isb);
}

__global__ void k_zerosh(unsigned short* __restrict__ p, int n8) {
  int i = blockIdx.x * blockDim.x + threadIdx.x;
  if (i < n8) { uint4 z = {0, 0, 0, 0}; *(uint4*)(p + (long)i * 8) = z; }
}

// tokenizer weight [192][49] (at element offset 9408) -> bf16 [192][64] zero-padded
__global__ void k_padtokw(const void* __restrict__ tw, bf16* __restrict__ dst,
                          const int* __restrict__ fl) {
  int isb = *fl;
  int i = blockIdx.x * blockDim.x + threadIdx.x;
  if (i >= 12288) return;
  int n = i >> 6, k = i & 63;
  float v = (k < 49) ? ldw(tw, 9408 + (long)n * 49 + k, isb) : 0.0f;
  dst[i] = f2bf(v);
}

// conv weight pack: dst[s][np][icp] bf16 from src [OC][ICT][9], channel remap feats|warp|flow|0
__global__ void k_packw(const void* __restrict__ src, bf16* __restrict__ dst,
                        int OC, int C, int ICT, int NP, int ICP, int n,
                        const int* __restrict__ fl) {
  int isb = *fl;
  int i = blockIdx.x * blockDim.x + threadIdx.x;
  if (i >= n) return;
  int s = i / (NP * ICP);
  int r = i - s * NP * ICP;
  int oc = r / ICP, icp = r - oc * ICP;
  float v = 0.0f;
  if (oc < OC) {
    int ic = -1;
    if (icp < C) ic = icp;
    else if (icp < 2 * C) ic = icp - C + C + 2;
    else if (icp < 2 * C + 2) ic = icp - 2 * C + C;
    if (ic >= 0 && ic < ICT) v = ldw(src, ((long)oc * ICT + ic) * 9 + s, isb);
  }
  dst[i] = f2bf(v);
}

// feats [F][C][HW] -> pixel-major bf16 [F][HW][C]; one thread per 8-channel group
__global__ void k_trans_feats(const void* __restrict__ in, bf16* __restrict__ Fp,
                              int F, int C, int HW, const int* __restrict__ fl) {
  int isb = *fl;
  int cpg = C >> 3;
  int n = F * HW * cpg;
  int i = blockIdx.x * blockDim.x + threadIdx.x;
  if (i >= n) return;
  int p = i % HW;
  int rem = i / HW;
  int c8 = rem % cpg;
  int f = rem / cpg;
  long base = (long)f * C * HW + (long)(c8 * 8) * HW + p;
  union { unsigned short u[8]; uint4 v; } pk;
#pragma unroll
  for (int j = 0; j < 8; ++j) pk.u[j] = bfr(ldw(in, base + (long)j * HW, isb));
  *(uint4*)((unsigned short*)Fp + ((long)f * HW + p) * C + c8 * 8) = pk.v;
}

// ---------------- decoder conv1: single-wave, barrier-free, spill-free ----------------
template <int C, int ICP, int NP, int WW, int LGW>
__global__ __launch_bounds__(64, 2) void k_conv1d(
    const bf16* __restrict__ Fp, const float* __restrict__ flow,
    const bf16* __restrict__ Wp, const float* __restrict__ bias,
    bf16* __restrict__ out) {
  constexpr int HH = WW, HW = WW * WW;
  constexpr int ACW = 18, APX = 54;
  constexpr int NK = ICP / 32;
  __shared__ unsigned short As[APX][40];
  __shared__ int pofs[APX];
  __shared__ int doff[APX][4];
  __shared__ float dwt[APX][4];
  __shared__ float ffl[APX][2];
  int ln = threadIdx.x;
  int quad = ln >> 4, l16 = ln & 15;
  int n0 = blockIdx.x * 16, m0 = blockIdx.y * 16, b = blockIdx.z;
  int py0 = m0 >> LGW, px0 = m0 & (WW - 1);
  const unsigned short* fcur = (const unsigned short*)Fp + (long)b * HW * C;
  const unsigned short* fnxt = (const unsigned short*)Fp + (long)(b + 1) * HW * C;
  const float* fl = flow + (long)b * 2 * HW;
  if (ln < APX) {
    int sr = ln / ACW, sc = ln - sr * ACW;
    int py = py0 + sr - 1, px = px0 + sc - 1;
    bool in = py >= 0 && py < HH && px >= 0 && px < WW;
    int p = in ? (py * WW + px) : 0;
    pofs[ln] = in ? p * C : -1;
    float fx = in ? fl[p] : 0.0f, fy = in ? fl[HW + p] : 0.0f;
    float x = fminf(fmaxf((float)px + fx, 0.0f), (float)(WW - 1));
    float y = fminf(fmaxf((float)py + fy, 0.0f), (float)(HH - 1));
    int x0 = (int)floorf(x), y0 = (int)floorf(y);
    int x1 = min(x0 + 1, WW - 1), y1 = min(y0 + 1, HH - 1);
    float wx = x - (float)x0, wy = y - (float)y0;
    dwt[ln][0] = in ? (1 - wx) * (1 - wy) : 0.0f;
    dwt[ln][1] = in ? wx * (1 - wy) : 0.0f;
    dwt[ln][2] = in ? (1 - wx) * wy : 0.0f;
    dwt[ln][3] = in ? wx * wy : 0.0f;
    doff[ln][0] = (y0 * WW + x0) * C; doff[ln][1] = (y0 * WW + x1) * C;
    doff[ln][2] = (y1 * WW + x0) * C; doff[ln][3] = (y1 * WW + x1) * C;
    ffl[ln][0] = in ? fx : 0.0f; ffl[ln][1] = in ? fy : 0.0f;
  }
  const unsigned short* wrow = (const unsigned short*)Wp + (long)(n0 + l16) * ICP + quad * 8;
  f32x4 ac0 = {}, ac1 = {}, ac2 = {};
  for (int kc = 0; kc < NK; ++kc) {
    int chb = kc * 32;
    if (chb < C) {
      uint4 arg[4];
#pragma unroll
      for (int j = 0; j < 4; ++j) {
        int idx = ln + j * 64;
        if (idx < APX * 4) {
          int ap = idx >> 2, c4 = idx & 3;
          int po = pofs[ap];
          uint4 z = {0, 0, 0, 0};
          arg[j] = (po >= 0) ? *(const uint4*)(fcur + po + chb + c4 * 8) : z;
        }
      }
#pragma unroll
      for (int j = 0; j < 4; ++j) {
        int idx = ln + j * 64;
        if (idx < APX * 4) {
          int ap = idx >> 2, c4 = idx & 3;
          *(uint4*)&As[ap][c4 * 8] = arg[j];
        }
      }
    } else if (chb < 2 * C) {
#pragma unroll
      for (int j = 0; j < 4; ++j) {
        int idx = ln + j * 64;
        if (idx < APX * 4) {
          int ap = idx >> 2, c4 = idx & 3;
          int c = chb - C + c4 * 8;
          uint4 v0 = *(const uint4*)(fnxt + doff[ap][0] + c);
          uint4 v1 = *(const uint4*)(fnxt + doff[ap][1] + c);
          uint4 v2 = *(const uint4*)(fnxt + doff[ap][2] + c);
          uint4 v3 = *(const uint4*)(fnxt + doff[ap][3] + c);
          float q0 = dwt[ap][0], q1 = dwt[ap][1], q2 = dwt[ap][2], q3 = dwt[ap][3];
          union { unsigned short u[8]; uint4 v; } a0 = {.v = v0}, a1 = {.v = v1},
                                                  a2 = {.v = v2}, a3 = {.v = v3}, o;
#pragma unroll
          for (int e = 0; e < 8; ++e)
            o.u[e] = bfr(shf(a0.u[e]) * q0 + shf(a1.u[e]) * q1 +
                         shf(a2.u[e]) * q2 + shf(a3.u[e]) * q3);
          *(uint4*)&As[ap][c4 * 8] = o.v;
        }
      }
    } else {
#pragma unroll
      for (int j = 0; j < 4; ++j) {
        int idx = ln + j * 64;
        if (idx < APX * 4) {
          int ap = idx >> 2, c4 = idx & 3;
          union { unsigned short u[8]; uint4 v; } o = { .v = {0, 0, 0, 0} };
          if (c4 == 0) { o.u[0] = bfr(ffl[ap][0]); o.u[1] = bfr(ffl[ap][1]); }
          *(uint4*)&As[ap][c4 * 8] = o.v;
        }
      }
    }
#pragma unroll
    for (int s = 0; s < 9; ++s) {
      int ky = s / 3, kx = s - ky * 3;
      bf16x8 af = *(const bf16x8*)&As[ky * ACW + l16 + kx][quad * 8];
      bf16x8 wf = *(const bf16x8*)(wrow + (long)s * NP * ICP + chb);
      if (s % 3 == 0)      ac0 = __builtin_amdgcn_mfma_f32_16x16x32_bf16(af, wf, ac0, 0, 0, 0);
      else if (s % 3 == 1) ac1 = __builtin_amdgcn_mfma_f32_16x16x32_bf16(af, wf, ac1, 0, 0, 0);
      else                 ac2 = __builtin_amdgcn_mfma_f32_16x16x32_bf16(af, wf, ac2, 0, 0, 0);
    }
  }
  int n = n0 + l16;
  float bv = bias[n];
  long rowbase = (long)b * (HH + 2) * (WW + 2) + (long)(py0 + 1) * (WW + 2);
#pragma unroll
  for (int r = 0; r < 4; ++r) {
    int px = px0 + quad * 4 + r;
    float v = gelu_exact(ac0[r] + ac1[r] + ac2[r] + bv);
    ((unsigned short*)out)[(rowbase + px + 1) * NP + n] = bfr(v);
  }
}

// ---------------- decoder conv2: wave-per-pixel dual dot (N=2, K=9*C) ----------------
template <int C, int WW, int LGW>
__global__ __launch_bounds__(256) void k_conv2_dot(
    const bf16* __restrict__ mid, const bf16* __restrict__ Wq,
    const float* __restrict__ bias, float* __restrict__ cur) {
  constexpr int HH = WW;
  constexpr int HW = HH * WW;
  constexpr int Wp2 = WW + 2;
  constexpr int CPL = C / 64;  // channels per lane (2 or 1)
  int tid = threadIdx.x, wv = tid >> 6, ln = tid & 63;
  int gw = blockIdx.x * 4 + wv;
  int b = gw >> (2 * LGW);
  int p = gw & (HW - 1);
  int py = p >> LGW, px = p & (WW - 1);
  float r0 = cur[((long)b * 2 + 0) * HW + p];
  float r1 = cur[((long)b * 2 + 1) * HW + p];
  float b0 = bias[0], b1 = bias[1];
  const unsigned short* base = (const unsigned short*)mid +
      ((long)b * (HH + 2) * Wp2 + (long)py * Wp2 + px) * C + ln * CPL;
  const unsigned short* wb = (const unsigned short*)Wq + ln * CPL;
  float s0 = 0.0f, s1 = 0.0f;
#pragma unroll
  for (int t = 0; t < 9; ++t) {
    int dy = t / 3, dx = t - dy * 3;
    const unsigned short* ar = base + ((long)dy * Wp2 + dx) * C;
    const unsigned short* w0r = wb + (long)(t * 16 + 0) * C;
    const unsigned short* w1r = wb + (long)(t * 16 + 1) * C;
    if (CPL == 2) {
      unsigned int a = *(const unsigned int*)ar;
      unsigned int q0 = *(const unsigned int*)w0r;
      unsigned int q1 = *(const unsigned int*)w1r;
      float a0 = shf((unsigned short)a), a1 = shf((unsigned short)(a >> 16));
      s0 += a0 * shf((unsigned short)q0) + a1 * shf((unsigned short)(q0 >> 16));
      s1 += a0 * shf((unsigned short)q1) + a1 * shf((unsigned short)(q1 >> 16));
    } else {
      float a0 = shf(ar[0]);
      s0 += a0 * shf(w0r[0]);
      s1 += a0 * shf(w1r[0]);
    }
  }
#pragma unroll
  for (int o = 32; o; o >>= 1) { s0 += __shfl_xor(s0, o); s1 += __shfl_xor(s1, o); }
  if (ln == 0) {
    cur[((long)b * 2 + 0) * HW + p] = s0 + b0 + r0;
    cur[((long)b * 2 + 1) * HW + p] = s1 + b1 + r1;
  }
}

// ---------------- local correlation from pixel-major bf16 Fp2, bf16 out, stride 64 -------
__global__ void k_corr(const bf16* __restrict__ Fp2, bf16* __restrict__ corrT) {
  __shared__ unsigned short f1r[128];
  int p = blockIdx.x;
  int b = blockIdx.y;
  int t = threadIdx.x;  // 64
  const unsigned short* f1 = (const unsigned short*)Fp2 + ((long)b * 1024 + p) * 128;
  if (t < 16) *(uint4*)&f1r[t * 8] = *(const uint4*)(f1 + t * 8);
  __syncthreads();
  long rowo = ((long)b * 1024 + p) * 64;
  if (t < 49) {
    int dy = t / 7 - 3, dx = t % 7 - 3;
    int h = p >> 5, w = p & 31;
    int p2 = (((h - dy) & 31) << 5) | ((w - dx) & 31);
    const unsigned short* f2 = (const unsigned short*)Fp2 + ((long)(b + 1) * 1024 + p2) * 128;
    float s = 0.0f;
    for (int c = 0; c < 128; c += 8) {
      union { unsigned short u[8]; uint4 v; } av = { .v = *(const uint4*)&f1r[c] };
      union { unsigned short u[8]; uint4 v; } bv = { .v = *(const uint4*)(f2 + c) };
#pragma unroll
      for (int j = 0; j < 8; ++j) s += shf(av.u[j]) * shf(bv.u[j]);
    }
    corrT[rowo + t] = f2bf(s * 0.08838834764831845f);
  } else {
    corrT[rowo + t] = f2bf(0.0f);
  }
}

// ================= persistent transformer megakernel =================
// 256 blocks x 256 threads (1 block/CU -> co-residency guaranteed). Contention-free
// flag barrier: each block stores a monotonic phase number to its OWN cacheline
// (parallel, no RMW chains); block 0's 256 threads poll the 256 distinct flags in
// parallel, then publish gen; everyone polls gen (read-shared). One release fence
// before arrival, one acquire fence after departure.

DEV void gridbar(int* flags, int* gen, int ph) {
  __syncthreads();
  if (threadIdx.x == 0) {
    __builtin_amdgcn_fence(__ATOMIC_RELEASE, "agent");
    __hip_atomic_store(&flags[blockIdx.x * 32], ph, __ATOMIC_RELAXED,
                       __HIP_MEMORY_SCOPE_AGENT);
  }
  if (blockIdx.x == 0) {
    while (__hip_atomic_load(&flags[threadIdx.x * 32], __ATOMIC_RELAXED,
                             __HIP_MEMORY_SCOPE_AGENT) < ph)
      __builtin_amdgcn_s_sleep(1);
    __syncthreads();
    if (threadIdx.x == 0)
      __hip_atomic_store(gen, ph, __ATOMIC_RELAXED, __HIP_MEMORY_SCOPE_AGENT);
  }
  if (threadIdx.x == 0) {
    while (__hip_atomic_load(gen, __ATOMIC_RELAXED, __HIP_MEMORY_SCOPE_AGENT) < ph)
      __builtin_amdgcn_s_sleep(2);
    __builtin_amdgcn_fence(__ATOMIC_ACQUIRE, "agent");
  }
  __syncthreads();
}

// wave-level GEMM phase: 16 rows x 64 cols per tile, tiles strided over 1024 waves.
// AMODE: 0 fp32 A; 1 bf16 A; 2 fused attention merge; 3 fused LayerNorm.
template <int KT, int ACT, bool HASRES, int AMODE, int OUTBF, int VT>
DEV void gemm_ph(unsigned short* wls, int gw, int ln,
                 const void* A, const void* W, long woff,
                 const void* bias, long boff, int isbb,
                 const float* res, void* C, int N, int isb,
                 const unsigned short* mop, const float* mml, bf16* vtout,
                 const void* lnw, long lnwoff, const void* lnb, long lnboff) {
  constexpr int NK = KT / 32;
  int quad = ln >> 4, l16 = ln & 15;
  int ntn = N >> 6;
  int ntiles = 128 * ntn;
  for (int t = gw; t < ntiles; t += 1024) {
    int tn = t % ntn, tm = t / ntn;
    int m0 = tm * 16, n0 = tn * 64;
    if constexpr (AMODE == 3) {
      int row = ln >> 2, j = ln & 3;
      const float* xr = (const float*)A + (long)(m0 + row) * 192 + j * 48;
      float av[48];
#pragma unroll
      for (int q = 0; q < 12; ++q) {
        float4 v = *(const float4*)(xr + q * 4);
        av[q * 4 + 0] = v.x; av[q * 4 + 1] = v.y;
        av[q * 4 + 2] = v.z; av[q * 4 + 3] = v.w;
      }
      float sum = 0.0f;
#pragma unroll
      for (int q = 0; q < 48; ++q) sum += av[q];
      sum += __shfl_xor(sum, 1);
      sum += __shfl_xor(sum, 2);
      float mean = sum * (1.0f / 192.0f);
      float vs = 0.0f;
#pragma unroll
      for (int q = 0; q < 48; ++q) { float d = av[q] - mean; vs += d * d; }
      vs += __shfl_xor(vs, 1);
      vs += __shfl_xor(vs, 2);
      float rstd = rsqrtf(vs * (1.0f / 192.0f) + 1e-5f);
#pragma unroll
      for (int g = 0; g < 6; ++g) {
        union { unsigned short u[8]; uint4 v; } pk;
#pragma unroll
        for (int e = 0; e < 8; ++e) {
          long k = j * 48 + g * 8 + e;
          float gg = ldw(lnw, lnwoff + k, isb);
          float bb = ldw(lnb, lnboff + k, isb);
          pk.u[e] = bfr((av[g * 8 + e] - mean) * rstd * gg + bb);
        }
        *(uint4*)&wls[row * 200 + j * 48 + g * 8] = pk.v;
      }
    } else if constexpr (AMODE == 2) {
      int row = ln >> 2, j = ln & 3;
      int m = m0 + row;
      int rr = m & 1023, bb = m >> 10;
      long idx[4];
      float ms[4], ls[4];
      float Ms = -1e30f;
#pragma unroll
      for (int s = 0; s < 4; ++s) {
        idx[s] = (((long)s * 2 + bb) * 4 + j) * 1024 + rr;
        ms[s] = mml[idx[s] * 2];
        ls[s] = mml[idx[s] * 2 + 1];
        Ms = fmaxf(Ms, ms[s]);
      }
      float e4[4], L = 0.0f;
#pragma unroll
      for (int s = 0; s < 4; ++s) { e4[s] = __expf(ms[s] - Ms); L += ls[s] * e4[s]; }
      float invL = 1.0f / L;
#pragma unroll
      for (int g = 0; g < 6; ++g) {
        union { unsigned short u[8]; uint4 v; } pk;
#pragma unroll
        for (int e2 = 0; e2 < 8; ++e2) {
          float o = 0.0f;
#pragma unroll
          for (int s = 0; s < 4; ++s) o += shf(mop[idx[s] * 48 + g * 8 + e2]) * e4[s];
          pk.u[e2] = bfr(o * invL);
        }
        *(uint4*)&wls[row * 200 + j * 48 + g * 8] = pk.v;
      }
    }
    f32x4 acc[4] = {};
    auto lda = [&](int kc) -> bf16x8 {
      if constexpr (AMODE >= 2) {
        return *(const bf16x8*)&wls[l16 * 200 + kc * 32 + quad * 8];
      } else if constexpr (AMODE == 1) {
        return *(const bf16x8*)((const unsigned short*)A + (long)(m0 + l16) * KT + kc * 32 + quad * 8);
      } else {
        const float* ap = (const float*)A + (long)(m0 + l16) * KT + kc * 32 + quad * 8;
        float4 a0 = *(const float4*)ap;
        float4 a1 = *(const float4*)(ap + 4);
        union { unsigned short u[8]; bf16x8 v; } pk;
        pk.u[0] = bfr(a0.x); pk.u[1] = bfr(a0.y); pk.u[2] = bfr(a0.z); pk.u[3] = bfr(a0.w);
        pk.u[4] = bfr(a1.x); pk.u[5] = bfr(a1.y); pk.u[6] = bfr(a1.z); pk.u[7] = bfr(a1.w);
        return pk.v;
      }
    };
    if (isb) {
      const unsigned short* wb = (const unsigned short*)W + woff + (long)l16 * KT + quad * 8;
      for (int kc = 0; kc < NK; ++kc) {
        bf16x8 af = lda(kc);
#pragma unroll
        for (int nt = 0; nt < 4; ++nt) {
          bf16x8 wf = *(const bf16x8*)(wb + (long)(n0 + nt * 16) * KT + kc * 32);
          acc[nt] = __builtin_amdgcn_mfma_f32_16x16x32_bf16(af, wf, acc[nt], 0, 0, 0);
        }
      }
    } else {
      const float* wb = (const float*)W + woff + (long)l16 * KT + quad * 8;
      for (int kc = 0; kc < NK; ++kc) {
        bf16x8 af = lda(kc);
#pragma unroll
        for (int nt = 0; nt < 4; ++nt) {
          const float* wp = wb + (long)(n0 + nt * 16) * KT + kc * 32;
          float4 w0 = *(const float4*)wp;
          float4 w1 = *(const float4*)(wp + 4);
          union { unsigned short u[8]; bf16x8 v; } pk;
          pk.u[0] = bfr(w0.x); pk.u[1] = bfr(w0.y); pk.u[2] = bfr(w0.z); pk.u[3] = bfr(w0.w);
          pk.u[4] = bfr(w1.x); pk.u[5] = bfr(w1.y); pk.u[6] = bfr(w1.z); pk.u[7] = bfr(w1.w);
          acc[nt] = __builtin_amdgcn_mfma_f32_16x16x32_bf16(af, pk.v, acc[nt], 0, 0, 0);
        }
      }
    }
#pragma unroll
    for (int nt = 0; nt < 4; ++nt) {
      int n = n0 + nt * 16 + l16;
      float bv = ldw(bias, boff + n, isbb);
#pragma unroll
      for (int r = 0; r < 4; ++r) {
        int m = m0 + quad * 4 + r;
        float v = acc[nt][r] + bv;
        if (HASRES) v += res[(long)m * N + n];
        if (ACT == 1) v = gelu_exact(v);
        if (OUTBF) ((bf16*)C)[(long)m * N + n] = f2bf(v);
        else ((float*)C)[(long)m * N + n] = v;
        if constexpr (VT) {
          if (n >= 384) {
            int hh = (n - 384) / 48, dd = (n - 384) % 48;
            int row = m & 1023, bb = m >> 10;
            vtout[((long)(bb * 4 + hh) * 48 + dd) * 1024 + row] = f2bf(v);
          }
        }
      }
    }
  }
}

// attention phase: 512 units strided over 256 blocks (exactly 2 each)
DEV void attn_ph(unsigned short* SM, int bid, int tid,
                 const bf16* qkv, const bf16* vt,
                 unsigned short* opart, float* ml) {
  unsigned short* Qs = SM;              // [64][72]
  unsigned short* Ks = SM + 64 * 72;    // [64][72]
  unsigned short* Vs = SM + 128 * 72;   // [48][72]
  unsigned short* Ps = SM + 176 * 72;   // [64][72]
  int wv = tid >> 6, ln = tid & 63, quad = ln >> 4, l16 = ln & 15;
  const float SC = 0.14433756729740643f;
  for (int u = bid; u < 512; u += 256) {
    int bx = u & 63;
    int h = (u >> 6) & 3, b = u >> 8;
    int qt = bx >> 2, s = bx & 3;
    int q0 = qt * 64;
    const unsigned short* qp = (const unsigned short*)qkv + (long)b * 1024 * 576;
    const unsigned short* vp = (const unsigned short*)vt + ((long)(b * 4 + h) * 48) * 1024;
    for (int i = tid; i < 384; i += 256) {
      int r = i / 6, c = i % 6;
      *(uint4*)&Qs[r * 72 + c * 8] = *(const uint4*)(qp + (long)(q0 + r) * 576 + h * 48 + c * 8);
    }
    for (int i = tid; i < 128; i += 256) {
      int r = i >> 1, c = 6 + (i & 1);
      uint4 z = {0, 0, 0, 0};
      *(uint4*)&Qs[r * 72 + c * 8] = z;
    }
    float m[4] = {-1e30f, -1e30f, -1e30f, -1e30f};
    float l[4] = {0.0f, 0.0f, 0.0f, 0.0f};
    f32x4 accO[3] = {};
    for (int kc = s * 4; kc < s * 4 + 4; ++kc) {
      int k0 = kc * 64;
      for (int i = tid; i < 384; i += 256) {
        int r = i / 6, c = i % 6;
        *(uint4*)&Ks[r * 72 + c * 8] =
            *(const uint4*)(qp + (long)(k0 + r) * 576 + 192 + h * 48 + c * 8);
      }
      for (int i = tid; i < 128; i += 256) {
        int r = i >> 1, c = 6 + (i & 1);
        uint4 z = {0, 0, 0, 0};
        *(uint4*)&Ks[r * 72 + c * 8] = z;
      }
      for (int i = tid; i < 384; i += 256) {
        int d = i >> 3, c = i & 7;
        *(uint4*)&Vs[d * 72 + c * 8] = *(const uint4*)(vp + (long)d * 1024 + k0 + c * 8);
      }
      __syncthreads();
      f32x4 accS[4] = {};
      bf16x8 a0 = *(const bf16x8*)&Qs[(wv * 16 + l16) * 72 + quad * 8];
      bf16x8 a1 = *(const bf16x8*)&Qs[(wv * 16 + l16) * 72 + 32 + quad * 8];
#pragma unroll
      for (int ct = 0; ct < 4; ++ct) {
        bf16x8 b0 = *(const bf16x8*)&Ks[(ct * 16 + l16) * 72 + quad * 8];
        bf16x8 b1 = *(const bf16x8*)&Ks[(ct * 16 + l16) * 72 + 32 + quad * 8];
        accS[ct] = __builtin_amdgcn_mfma_f32_16x16x32_bf16(a0, b0, accS[ct], 0, 0, 0);
        accS[ct] = __builtin_amdgcn_mfma_f32_16x16x32_bf16(a1, b1, accS[ct], 0, 0, 0);
      }
#pragma unroll
      for (int r = 0; r < 4; ++r) {
        float s0 = accS[0][r] * SC, s1 = accS[1][r] * SC;
        float s2 = accS[2][r] * SC, s3 = accS[3][r] * SC;
        float mx = fmaxf(fmaxf(s0, s1), fmaxf(s2, s3));
        for (int o = 8; o; o >>= 1) mx = fmaxf(mx, __shfl_xor(mx, o));
        float mn = fmaxf(m[r], mx);
        float alpha = __expf(m[r] - mn);
        float p0 = __expf(s0 - mn), p1 = __expf(s1 - mn);
        float p2 = __expf(s2 - mn), p3 = __expf(s3 - mn);
        float rs = p0 + p1 + p2 + p3;
        for (int o = 8; o; o >>= 1) rs += __shfl_xor(rs, o);
        m[r] = mn;
        l[r] = l[r] * alpha + rs;
        accO[0][r] *= alpha; accO[1][r] *= alpha; accO[2][r] *= alpha;
        int prow = wv * 16 + quad * 4 + r;
        Ps[prow * 72 + l16]      = bfr(p0);
        Ps[prow * 72 + 16 + l16] = bfr(p1);
        Ps[prow * 72 + 32 + l16] = bfr(p2);
        Ps[prow * 72 + 48 + l16] = bfr(p3);
      }
      bf16x8 pf0 = *(const bf16x8*)&Ps[(wv * 16 + l16) * 72 + quad * 8];
      bf16x8 pf1 = *(const bf16x8*)&Ps[(wv * 16 + l16) * 72 + 32 + quad * 8];
#pragma unroll
      for (int ct = 0; ct < 3; ++ct) {
        bf16x8 v0 = *(const bf16x8*)&Vs[(ct * 16 + l16) * 72 + quad * 8];
        bf16x8 v1 = *(const bf16x8*)&Vs[(ct * 16 + l16) * 72 + 32 + quad * 8];
        accO[ct] = __builtin_amdgcn_mfma_f32_16x16x32_bf16(pf0, v0, accO[ct], 0, 0, 0);
        accO[ct] = __builtin_amdgcn_mfma_f32_16x16x32_bf16(pf1, v1, accO[ct], 0, 0, 0);
      }
      __syncthreads();
    }
    long base = (((long)s * 2 + b) * 4 + h) * 1024;
#pragma unroll
    for (int r = 0; r < 4; ++r) {
      int row = q0 + wv * 16 + quad * 4 + r;
#pragma unroll
      for (int ct = 0; ct < 3; ++ct)
        opart[(base + row) * 48 + ct * 16 + l16] = bfr(accO[ct][r]);
      if (l16 == 0) {
        ml[(base + row) * 2]     = m[r];
        ml[(base + row) * 2 + 1] = l[r];
      }
    }
  }
}

__global__ __launch_bounds__(256, 2) void k_mega(
    const int* flag, int* barflags, int* bargen,
    float* x, const bf16* corrTb, const bf16* wtok, const void* tok_b,
    bf16* qkvbb, bf16* vtb, unsigned short* opart, float* mlbuf,
    bf16* hidb, float* headh, float* cur,
    const void* lcm_ln1_w, const void* lcm_ln1_b, const void* lcm_in_w, const void* lcm_in_b,
    const void* lcm_out_w, const void* lcm_out_b, const void* lcm_ln2_w, const void* lcm_ln2_b,
    const void* lcm_mlp_w1, const void* lcm_mlp_b1, const void* lcm_mlp_w2, const void* lcm_mlp_b2,
    const void* gtr_ln1_w, const void* gtr_ln1_b, const void* gtr_in_w, const void* gtr_in_b,
    const void* gtr_out_w, const void* gtr_out_b, const void* gtr_ln2_w, const void* gtr_ln2_b,
    const void* gtr_mlp_w1, const void* gtr_mlp_b1, const void* gtr_mlp_w2, const void* gtr_mlp_b2,
    const void* head_w1, const void* head_b1, const void* head_w2, const void* head_b2) {
  __shared__ unsigned short SM[17280];  // attn: 240x72 | gemm: 4 waves x 16x200
  int tid = threadIdx.x, bid = blockIdx.x;
  int wv = tid >> 6, ln = tid & 63;
  int gw = bid * 4 + wv;
  unsigned short* wls = SM + wv * 3200;
  int isb = *flag;
  int ph = 0;
  // phase 0: tokenizer GEMM (A/W packed bf16, bias raw)
  gemm_ph<64, 0, false, 1, 0, 0>(wls, gw, ln, corrTb, wtok, 0, tok_b, 192, isb,
                                 nullptr, x, 192, 1, nullptr, nullptr, nullptr,
                                 nullptr, 0, nullptr, 0);
  gridbar(barflags, bargen, ++ph);
  for (int blk = 0; blk < 8; ++blk) {
    long i = (blk < 6) ? blk : (blk - 6);
    const void *ln1w, *ln1b, *inw, *inb, *ow, *ob, *ln2w, *ln2b, *w1, *b1, *w2, *b2;
    if (blk < 6) {
      ln1w = lcm_ln1_w; ln1b = lcm_ln1_b; inw = lcm_in_w; inb = lcm_in_b;
      ow = lcm_out_w; ob = lcm_out_b; ln2w = lcm_ln2_w; ln2b = lcm_ln2_b;
      w1 = lcm_mlp_w1; b1 = lcm_mlp_b1; w2 = lcm_mlp_w2; b2 = lcm_mlp_b2;
    } else {
      ln1w = gtr_ln1_w; ln1b = gtr_ln1_b; inw = gtr_in_w; inb = gtr_in_b;
      ow = gtr_out_w; ob = gtr_out_b; ln2w = gtr_ln2_w; ln2b = gtr_ln2_b;
      w1 = gtr_mlp_w1; b1 = gtr_mlp_b1; w2 = gtr_mlp_w2; b2 = gtr_mlp_b2;
    }
    long o1 = i * 192, o2 = i * 192, o3 = i * 110592, o4 = i * 576;
    long o5 = i * 36864, o6 = i * 192, o7 = i * 192, o8 = i * 192;
    long o9 = i * 147456, o10 = i * 768, o11 = i * 147456, o12 = i * 192;
    // LN1 + qkv (+V-transpose scatter)
    gemm_ph<192, 0, false, 3, 1, 1>(wls, gw, ln, x, inw, o3, inb, o4, isb,
                                    nullptr, qkvbb, 576, isb, nullptr, nullptr, vtb,
                                    ln1w, o1, ln1b, o2);
    gridbar(barflags, bargen, ++ph);
    attn_ph(SM, bid, tid, qkvbb, vtb, opart, mlbuf);
    gridbar(barflags, bargen, ++ph);
    // merge + out-proj (+residual, in-place x)
    gemm_ph<192, 0, true, 2, 0, 0>(wls, gw, ln, nullptr, ow, o5, ob, o6, isb,
                                   x, x, 192, isb, opart, mlbuf, nullptr,
                                   nullptr, 0, nullptr, 0);
    gridbar(barflags, bargen, ++ph);
    // LN2 + mlp1 (gelu)
    gemm_ph<192, 1, false, 3, 1, 0>(wls, gw, ln, x, w1, o9, b1, o10, isb,
                                    nullptr, hidb, 768, isb, nullptr, nullptr, nullptr,
                                    ln2w, o7, ln2b, o8);
    gridbar(barflags, bargen, ++ph);
    // mlp2 (+residual, in-place x)
    gemm_ph<768, 0, true, 1, 0, 0>(wls, gw, ln, hidb, w2, o11, b2, o12, isb,
                                   x, x, 192, isb, nullptr, nullptr, nullptr,
                                   nullptr, 0, nullptr, 0);
    gridbar(barflags, bargen, ++ph);
    if (blk == 5) {
      int gt = bid * 256 + tid;
      for (int e = gt; e < 196608; e += 65536)
        x[196608 + e] = 0.8f * x[196608 + e] + 0.2f * x[e];
      gridbar(barflags, bargen, ++ph);
    }
  }
  // head layer 1 (gelu, fp32 out)
  gemm_ph<192, 1, false, 0, 0, 0>(wls, gw, ln, x, head_w1, 0, head_b1, 0, isb,
                                  nullptr, headh, 192, isb, nullptr, nullptr, nullptr,
                                  nullptr, 0, nullptr, 0);
  gridbar(barflags, bargen, ++ph);
  // head layer 2: wave-per-output dot, writes cur [b][2][1024]
  for (int t2 = gw; t2 < 4096; t2 += 1024) {
    int m = t2 >> 1, n = t2 & 1;
    const float* a = headh + (long)m * 192;
    float s = 0.0f;
#pragma unroll
    for (int q = 0; q < 3; ++q) {
      int j = ln + q * 64;
      s += a[j] * ldw(head_w2, (long)n * 192 + j, isb);
    }
    for (int o = 32; o; o >>= 1) s += __shfl_xor(s, o);
    if (ln == 0) {
      int b = m >> 10, p = m & 1023;
      cur[((long)b * 2 + n) * 1024 + p] = s + ldw(head_b2, n, isb);
    }
  }
}

// ---------------- upsample / out ----------------
__global__ void k_upsample(const float* __restrict__ in, float* __restrict__ out) {
  int i = blockIdx.x * blockDim.x + threadIdx.x;
  if (i >= 2 * 2 * 64 * 64) return;
  int p = i & 4095;
  int bc = i >> 12;
  int oy = p >> 6, ox = p & 63;
  float sx = ox * (31.0f / 63.0f), sy = oy * (31.0f / 63.0f);
  int x0 = (int)sx, y0 = (int)sy;
  int x1 = min(x0 + 1, 31), y1 = min(y0 + 1, 31);
  float wx = sx - x0, wy = sy - y0;
  const float* ic = in + (long)bc * 1024;
  out[i] = ic[y0 * 32 + x0] * (1 - wx) * (1 - wy) + ic[y0 * 32 + x1] * wx * (1 - wy)
         + ic[y1 * 32 + x0] * (1 - wx) * wy      + ic[y1 * 32 + x1] * wx * wy;
}

__global__ void k_out(const float* __restrict__ cur2, void* __restrict__ out,
                      const int* __restrict__ fl) {
  int isb = *fl;
  int i = blockIdx.x * blockDim.x + threadIdx.x;
  if (i < 16384) {
    if (isb) ((bf16*)out)[i] = f2bf(cur2[i]);
    else ((float*)out)[i] = cur2[i];
  }
}

extern "C" void kernel_launch(void* const* d_in, const int* in_sizes, int n_in,
                              void* d_out, int out_size, void* d_ws, size_t ws_size,
                              hipStream_t stream) {
  const void* feats_l1 = d_in[0];
  const void* feats_l2 = d_in[1];
  const void* tok_w = d_in[3];
  const void* tok_b = d_in[4];
  const void* lcm_ln1_w = d_in[5];
  const void* lcm_ln1_b = d_in[6];
  const void* lcm_in_w  = d_in[7];
  const void* lcm_in_b  = d_in[8];
  const void* lcm_out_w = d_in[9];
  const void* lcm_out_b = d_in[10];
  const void* lcm_ln2_w = d_in[11];
  const void* lcm_ln2_b = d_in[12];
  const void* lcm_mlp_w1 = d_in[13];
  const void* lcm_mlp_b1 = d_in[14];
  const void* lcm_mlp_w2 = d_in[15];
  const void* lcm_mlp_b2 = d_in[16];
  const void* gtr_ln1_w = d_in[17];
  const void* gtr_ln1_b = d_in[18];
  const void* gtr_in_w  = d_in[19];
  const void* gtr_in_b  = d_in[20];
  const void* gtr_out_w = d_in[21];
  const void* gtr_out_b = d_in[22];
  const void* gtr_ln2_w = d_in[23];
  const void* gtr_ln2_b = d_in[24];
  const void* gtr_mlp_w1 = d_in[25];
  const void* gtr_mlp_b1 = d_in[26];
  const void* gtr_mlp_w2 = d_in[27];
  const void* gtr_mlp_b2 = d_in[28];
  const void* head_w1 = d_in[29];
  const void* head_b1 = d_in[30];
  const void* head_w2 = d_in[31];
  const void* head_b2 = d_in[32];
  const void* ref1_w1 = d_in[33];
  const void* ref1_b1 = d_in[34];
  const void* ref1_w2 = d_in[35];
  const void* ref1_b2 = d_in[36];
  const void* ref0_w1 = d_in[37];
  const void* ref0_b1 = d_in[38];
  const void* ref0_w2 = d_in[39];
  const void* ref0_b2 = d_in[40];
  (void)ws_size; (void)n_in; (void)in_sizes; (void)out_size;

  // ---- workspace layout (f-eq units; ~16.8 MB) ----
  int* flag = (int*)d_ws;
  int* bargen = (int*)d_ws + 64;      // own cacheline (byte 256), in F2 spare
  int* barflags = (int*)d_ws + 1024;  // 256 x 128B cachelines (bytes 4096..36863)
  float* wsf = (float*)d_ws;
  float* F2   = wsf + 16;             // 393216 (spare; holds barrier state only)
  float* rA   = F2 + 393216;          // 786432 : opart bf16
  float* rX   = rA + 786432;          // 393216 : residual x
  float* rT   = rX + 393216;          // 393216 : head-hidden | mid0packed
  float* rY   = rT + 393216;          // 393216 : mlbuf | mid1packed
  float* big  = rY + 393216;          // 1572864: qkv/vt/hid [0,851968) | Fp2+Fp1 tail
  float* fv   = big + 1572864;        // 4096 (unused)
  float* cur  = fv + 4096;            // 4096
  float* cur2 = cur + 4096;           // 16384
  float* cb1a = cur2 + 16384;         // 128
  float* cb1b = cb1a + 128;           // 16
  float* cb0a = cb1b + 16;            // 64
  float* cb0b = cb0a + 64;            // 16
  bf16* wtok  = (bf16*)(cb0b + 16);   // 12288 shorts
  float* wpk  = cb0b + 16 + 6144;
  bf16* w1p1 = (bf16*)wpk;            // 331776 shorts
  bf16* w1p2 = (bf16*)(wpk + 165888); // 18432 shorts
  bf16* w0p1 = (bf16*)(wpk + 175104); // 92160 shorts
  bf16* w0p2 = (bf16*)(wpk + 221184); // 9216 shorts

  float* x = rX;
  bf16* corrTb = (bf16*)big;
  bf16* qkvbb  = (bf16*)big;
  bf16* vtb    = (bf16*)(big + 655360);
  bf16* hidb   = (bf16*)big;
  unsigned short* opart = (unsigned short*)rA;  // [4][2][4][1024][48] bf16
  float* mlbuf = rY;                            // [4][2][4][1024][2] fp32
  float* headh = rT;
  bf16* mid0p = (bf16*)rT;
  bf16* mid1p = (bf16*)rY;
  bf16* Fp2   = (bf16*)(big + 851968);   // [3][1024][128] = 393216 shorts
  bf16* Fp1   = (bf16*)(big + 1048576);  // [3][4096][64]  = 786432 shorts

  k_detect<<<1, 256, 0, stream>>>((const unsigned short*)feats_l1, flag);
  k_zerobar<<<1, 256, 0, stream>>>(bargen, barflags);
  k_cvt<<<1, 256, 0, stream>>>(ref1_b1, cb1a, 128, flag);
  k_cvt<<<1, 256, 0, stream>>>(ref1_b2, cb1b, 2, flag);
  k_cvt<<<1, 256, 0, stream>>>(ref0_b1, cb0a, 64, flag);
  k_cvt<<<1, 256, 0, stream>>>(ref0_b2, cb0b, 2, flag);
  k_padtokw<<<48, 256, 0, stream>>>(tok_w, wtok, flag);
  k_packw<<<1296, 256, 0, stream>>>(ref1_w1, w1p1, 128, 128, 258, 128, 288, 331776, flag);
  k_packw<<<72, 256, 0, stream>>>(ref1_w2, w1p2, 2, 128, 128, 16, 128, 18432, flag);
  k_packw<<<360, 256, 0, stream>>>(ref0_w1, w0p1, 64, 64, 130, 64, 160, 92160, flag);
  k_packw<<<36, 256, 0, stream>>>(ref0_w2, w0p2, 2, 64, 64, 16, 64, 9216, flag);
  // pixel-major frames up front (big tail survives qkv/hid which use [0,851968))
  k_trans_feats<<<192, 256, 0, stream>>>(feats_l2, Fp2, 3, 128, 1024, flag);
  k_trans_feats<<<384, 256, 0, stream>>>(feats_l1, Fp1, 3, 64, 4096, flag);

  // ---- tokens: corr (from Fp2) ----
  k_corr<<<dim3(1024, 2), 64, 0, stream>>>(Fp2, corrTb);

  // ---- whole transformer + head as ONE persistent kernel (43 flag barriers) ----
  k_mega<<<256, 256, 0, stream>>>(
      flag, barflags, bargen, x, corrTb, wtok, tok_b,
      qkvbb, vtb, opart, mlbuf, hidb, headh, cur,
      lcm_ln1_w, lcm_ln1_b, lcm_in_w, lcm_in_b, lcm_out_w, lcm_out_b,
      lcm_ln2_w, lcm_ln2_b, lcm_mlp_w1, lcm_mlp_b1, lcm_mlp_w2, lcm_mlp_b2,
      gtr_ln1_w, gtr_ln1_b, gtr_in_w, gtr_in_b, gtr_out_w, gtr_out_b,
      gtr_ln2_w, gtr_ln2_b, gtr_mlp_w1, gtr_mlp_b1, gtr_mlp_w2, gtr_mlp_b2,
      head_w1, head_b1, head_w2, head_b2);

  // ---- decoder prep: zero mid buffers (borders must stay 0) ----
  k_zerosh<<<768, 256, 0, stream>>>((unsigned short*)rT, 196608);

  // ---- decoder level 1 (32x32): C=128, ICP=288, OC=128 ----
  for (int it = 0; it < 4; ++it) {
    k_conv1d<128, 288, 128, 32, 5><<<dim3(8, 64, 2), 64, 0, stream>>>(
        Fp2, cur, w1p1, cb1a, mid1p);
    k_conv2_dot<128, 32, 5><<<512, 256, 0, stream>>>(mid1p, w1p2, cb1b, cur);
  }
  k_upsample<<<64, 256, 0, stream>>>(cur, cur2);

  // ---- decoder level 0 (64x64): C=64, ICP=160, OC=64 ----
  for (int it = 0; it < 4; ++it) {
    k_conv1d<64, 160, 64, 64, 6><<<dim3(4, 256, 2), 64, 0, stream>>>(
        Fp1, cur2, w0p1, cb0a, mid0p);
    k_conv2_dot<64, 64, 6><<<2048, 256, 0, stream>>>(mid0p, w0p2, cb0b, cur2);
  }

  k_out<<<64, 256, 0, stream>>>(cur2, d_out, flag);
}

// Round 11
// 1138.966 us; speedup vs baseline: 4.0684x; 1.4401x over previous
//
#include <hip/hip_runtime.h>
#include <hip/hip_bf16.h>

typedef __hip_bfloat16 bf16;
typedef short bf16x8 __attribute__((ext_vector_type(8)));
typedef float f32x4 __attribute__((ext_vector_type(4)));

#define DEV __device__ __forceinline__

DEV float bf2f(bf16 v) { return __bfloat162float(v); }
DEV bf16 f2bf(float v) { return __float2bfloat16(v); }
DEV unsigned short bfr(float f) {
  bf16 h = __float2bfloat16(f);
  return *reinterpret_cast<unsigned short*>(&h);
}
DEV float shf(unsigned short u) {
  unsigned int x = ((unsigned int)u) << 16;
  return *reinterpret_cast<float*>(&x);
}
DEV float gelu_exact(float x) { return 0.5f * x * (1.0f + erff(x * 0.70710678118654752f)); }

DEV float ldw(const void* p, long i, int isb) {
  return isb ? __bfloat162float(((const bf16*)p)[i]) : ((const float*)p)[i];
}

// ---------------- dtype detection ----------------
__global__ void k_detect(const unsigned short* __restrict__ u, int* __restrict__ flag) {
  __shared__ int bad;
  if (threadIdx.x == 0) bad = 0;
  __syncthreads();
  for (int i = threadIdx.x; i < 8192; i += 256) {
    int expo = (u[i] >> 7) & 0xFF;
    if (expo >= 138) atomicOr(&bad, 1);
  }
  __syncthreads();
  if (threadIdx.x == 0) *flag = bad ? 0 : 1;
}

// ---------------- convert (bf16|fp32) -> fp32 ----------------
__global__ void k_cvt(const void* __restrict__ s, float* __restrict__ d, int n,
                      const int* __restrict__ fl) {
  int isb = *fl;
  int i = blockIdx.x * blockDim.x + threadIdx.x;
  if (i < n) d[i] = ldw(s, i, isb);
}

__global__ void k_zerosh(unsigned short* __restrict__ p, int n8) {
  int i = blockIdx.x * blockDim.x + threadIdx.x;
  if (i < n8) { uint4 z = {0, 0, 0, 0}; *(uint4*)(p + (long)i * 8) = z; }
}

// tokenizer weight [192][49] (at element offset 9408) -> bf16 [192][64] zero-padded
__global__ void k_padtokw(const void* __restrict__ tw, bf16* __restrict__ dst,
                          const int* __restrict__ fl) {
  int isb = *fl;
  int i = blockIdx.x * blockDim.x + threadIdx.x;
  if (i >= 12288) return;
  int n = i >> 6, k = i & 63;
  float v = (k < 49) ? ldw(tw, 9408 + (long)n * 49 + k, isb) : 0.0f;
  dst[i] = f2bf(v);
}

// conv weight pack: dst[s][np][icp] bf16 from src [OC][ICT][9]
__global__ void k_packw(const void* __restrict__ src, bf16* __restrict__ dst,
                        int OC, int C, int ICT, int NP, int ICP, int n,
                        const int* __restrict__ fl) {
  int isb = *fl;
  int i = blockIdx.x * blockDim.x + threadIdx.x;
  if (i >= n) return;
  int s = i / (NP * ICP);
  int r = i - s * NP * ICP;
  int oc = r / ICP, icp = r - oc * ICP;
  float v = 0.0f;
  if (oc < OC) {
    int ic = -1;
    if (icp < C) ic = icp;
    else if (icp < 2 * C) ic = icp - C + C + 2;
    else if (icp < 2 * C + 2) ic = icp - 2 * C + C;
    if (ic >= 0 && ic < ICT) v = ldw(src, ((long)oc * ICT + ic) * 9 + s, isb);
  }
  dst[i] = f2bf(v);
}

// feats [F][C][HW] -> pixel-major bf16 [F][HW][C]
__global__ void k_trans_feats(const void* __restrict__ in, bf16* __restrict__ Fp,
                              int F, int C, int HW, const int* __restrict__ fl) {
  int isb = *fl;
  int cpg = C >> 3;
  int n = F * HW * cpg;
  int i = blockIdx.x * blockDim.x + threadIdx.x;
  if (i >= n) return;
  int p = i % HW;
  int rem = i / HW;
  int c8 = rem % cpg;
  int f = rem / cpg;
  long base = (long)f * C * HW + (long)(c8 * 8) * HW + p;
  union { unsigned short u[8]; uint4 v; } pk;
#pragma unroll
  for (int j = 0; j < 8; ++j) pk.u[j] = bfr(ldw(in, base + (long)j * HW, isb));
  *(uint4*)((unsigned short*)Fp + ((long)f * HW + p) * C + c8 * 8) = pk.v;
}

// ---------------- decoder conv1: single-wave, barrier-free, spill-free ----------------
template <int C, int ICP, int NP, int WW, int LGW>
__global__ __launch_bounds__(64, 2) void k_conv1d(
    const bf16* __restrict__ Fp, const float* __restrict__ flow,
    const bf16* __restrict__ Wp, const float* __restrict__ bias,
    bf16* __restrict__ out) {
  constexpr int HH = WW, HW = WW * WW;
  constexpr int ACW = 18, APX = 54;
  constexpr int NK = ICP / 32;
  __shared__ unsigned short As[APX][40];
  __shared__ int pofs[APX];
  __shared__ int doff[APX][4];
  __shared__ float dwt[APX][4];
  __shared__ float ffl[APX][2];
  int ln = threadIdx.x;
  int quad = ln >> 4, l16 = ln & 15;
  int n0 = blockIdx.x * 16, m0 = blockIdx.y * 16, b = blockIdx.z;
  int py0 = m0 >> LGW, px0 = m0 & (WW - 1);
  const unsigned short* fcur = (const unsigned short*)Fp + (long)b * HW * C;
  const unsigned short* fnxt = (const unsigned short*)Fp + (long)(b + 1) * HW * C;
  const float* fl = flow + (long)b * 2 * HW;
  if (ln < APX) {
    int sr = ln / ACW, sc = ln - sr * ACW;
    int py = py0 + sr - 1, px = px0 + sc - 1;
    bool in = py >= 0 && py < HH && px >= 0 && px < WW;
    int p = in ? (py * WW + px) : 0;
    pofs[ln] = in ? p * C : -1;
    float fx = in ? fl[p] : 0.0f, fy = in ? fl[HW + p] : 0.0f;
    float x = fminf(fmaxf((float)px + fx, 0.0f), (float)(WW - 1));
    float y = fminf(fmaxf((float)py + fy, 0.0f), (float)(HH - 1));
    int x0 = (int)floorf(x), y0 = (int)floorf(y);
    int x1 = min(x0 + 1, WW - 1), y1 = min(y0 + 1, HH - 1);
    float wx = x - (float)x0, wy = y - (float)y0;
    dwt[ln][0] = in ? (1 - wx) * (1 - wy) : 0.0f;
    dwt[ln][1] = in ? wx * (1 - wy) : 0.0f;
    dwt[ln][2] = in ? (1 - wx) * wy : 0.0f;
    dwt[ln][3] = in ? wx * wy : 0.0f;
    doff[ln][0] = (y0 * WW + x0) * C; doff[ln][1] = (y0 * WW + x1) * C;
    doff[ln][2] = (y1 * WW + x0) * C; doff[ln][3] = (y1 * WW + x1) * C;
    ffl[ln][0] = in ? fx : 0.0f; ffl[ln][1] = in ? fy : 0.0f;
  }
  const unsigned short* wrow = (const unsigned short*)Wp + (long)(n0 + l16) * ICP + quad * 8;
  f32x4 ac0 = {}, ac1 = {}, ac2 = {};
  for (int kc = 0; kc < NK; ++kc) {
    int chb = kc * 32;
    if (chb < C) {
      uint4 arg[4];
#pragma unroll
      for (int j = 0; j < 4; ++j) {
        int idx = ln + j * 64;
        if (idx < APX * 4) {
          int ap = idx >> 2, c4 = idx & 3;
          int po = pofs[ap];
          uint4 z = {0, 0, 0, 0};
          arg[j] = (po >= 0) ? *(const uint4*)(fcur + po + chb + c4 * 8) : z;
        }
      }
#pragma unroll
      for (int j = 0; j < 4; ++j) {
        int idx = ln + j * 64;
        if (idx < APX * 4) {
          int ap = idx >> 2, c4 = idx & 3;
          *(uint4*)&As[ap][c4 * 8] = arg[j];
        }
      }
    } else if (chb < 2 * C) {
#pragma unroll
      for (int j = 0; j < 4; ++j) {
        int idx = ln + j * 64;
        if (idx < APX * 4) {
          int ap = idx >> 2, c4 = idx & 3;
          int c = chb - C + c4 * 8;
          uint4 v0 = *(const uint4*)(fnxt + doff[ap][0] + c);
          uint4 v1 = *(const uint4*)(fnxt + doff[ap][1] + c);
          uint4 v2 = *(const uint4*)(fnxt + doff[ap][2] + c);
          uint4 v3 = *(const uint4*)(fnxt + doff[ap][3] + c);
          float q0 = dwt[ap][0], q1 = dwt[ap][1], q2 = dwt[ap][2], q3 = dwt[ap][3];
          union { unsigned short u[8]; uint4 v; } a0 = {.v = v0}, a1 = {.v = v1},
                                                  a2 = {.v = v2}, a3 = {.v = v3}, o;
#pragma unroll
          for (int e = 0; e < 8; ++e)
            o.u[e] = bfr(shf(a0.u[e]) * q0 + shf(a1.u[e]) * q1 +
                         shf(a2.u[e]) * q2 + shf(a3.u[e]) * q3);
          *(uint4*)&As[ap][c4 * 8] = o.v;
        }
      }
    } else {
#pragma unroll
      for (int j = 0; j < 4; ++j) {
        int idx = ln + j * 64;
        if (idx < APX * 4) {
          int ap = idx >> 2, c4 = idx & 3;
          union { unsigned short u[8]; uint4 v; } o = { .v = {0, 0, 0, 0} };
          if (c4 == 0) { o.u[0] = bfr(ffl[ap][0]); o.u[1] = bfr(ffl[ap][1]); }
          *(uint4*)&As[ap][c4 * 8] = o.v;
        }
      }
    }
#pragma unroll
    for (int s = 0; s < 9; ++s) {
      int ky = s / 3, kx = s - ky * 3;
      bf16x8 af = *(const bf16x8*)&As[ky * ACW + l16 + kx][quad * 8];
      bf16x8 wf = *(const bf16x8*)(wrow + (long)s * NP * ICP + chb);
      if (s % 3 == 0)      ac0 = __builtin_amdgcn_mfma_f32_16x16x32_bf16(af, wf, ac0, 0, 0, 0);
      else if (s % 3 == 1) ac1 = __builtin_amdgcn_mfma_f32_16x16x32_bf16(af, wf, ac1, 0, 0, 0);
      else                 ac2 = __builtin_amdgcn_mfma_f32_16x16x32_bf16(af, wf, ac2, 0, 0, 0);
    }
  }
  int n = n0 + l16;
  float bv = bias[n];
  long rowbase = (long)b * (HH + 2) * (WW + 2) + (long)(py0 + 1) * (WW + 2);
#pragma unroll
  for (int r = 0; r < 4; ++r) {
    int px = px0 + quad * 4 + r;
    float v = gelu_exact(ac0[r] + ac1[r] + ac2[r] + bv);
    ((unsigned short*)out)[(rowbase + px + 1) * NP + n] = bfr(v);
  }
}

// ---------------- decoder conv2: wave-per-pixel dual dot (N=2, K=9*C) ----------------
template <int C, int WW, int LGW>
__global__ __launch_bounds__(256) void k_conv2_dot(
    const bf16* __restrict__ mid, const bf16* __restrict__ Wq,
    const float* __restrict__ bias, float* __restrict__ cur) {
  constexpr int HH = WW;
  constexpr int HW = HH * WW;
  constexpr int Wp2 = WW + 2;
  constexpr int CPL = C / 64;
  int tid = threadIdx.x, wv = tid >> 6, ln = tid & 63;
  int gw = blockIdx.x * 4 + wv;
  int b = gw >> (2 * LGW);
  int p = gw & (HW - 1);
  int py = p >> LGW, px = p & (WW - 1);
  float r0 = cur[((long)b * 2 + 0) * HW + p];
  float r1 = cur[((long)b * 2 + 1) * HW + p];
  float b0 = bias[0], b1 = bias[1];
  const unsigned short* base = (const unsigned short*)mid +
      ((long)b * (HH + 2) * Wp2 + (long)py * Wp2 + px) * C + ln * CPL;
  const unsigned short* wb = (const unsigned short*)Wq + ln * CPL;
  float s0 = 0.0f, s1 = 0.0f;
#pragma unroll
  for (int t = 0; t < 9; ++t) {
    int dy = t / 3, dx = t - dy * 3;
    const unsigned short* ar = base + ((long)dy * Wp2 + dx) * C;
    const unsigned short* w0r = wb + (long)(t * 16 + 0) * C;
    const unsigned short* w1r = wb + (long)(t * 16 + 1) * C;
    if (CPL == 2) {
      unsigned int a = *(const unsigned int*)ar;
      unsigned int q0 = *(const unsigned int*)w0r;
      unsigned int q1 = *(const unsigned int*)w1r;
      float a0 = shf((unsigned short)a), a1 = shf((unsigned short)(a >> 16));
      s0 += a0 * shf((unsigned short)q0) + a1 * shf((unsigned short)(q0 >> 16));
      s1 += a0 * shf((unsigned short)q1) + a1 * shf((unsigned short)(q1 >> 16));
    } else {
      float a0 = shf(ar[0]);
      s0 += a0 * shf(w0r[0]);
      s1 += a0 * shf(w1r[0]);
    }
  }
#pragma unroll
  for (int o = 32; o; o >>= 1) { s0 += __shfl_xor(s0, o); s1 += __shfl_xor(s1, o); }
  if (ln == 0) {
    cur[((long)b * 2 + 0) * HW + p] = s0 + b0 + r0;
    cur[((long)b * 2 + 1) * HW + p] = s1 + b1 + r1;
  }
}

// ---------------- local correlation ----------------
__global__ void k_corr(const bf16* __restrict__ Fp2, bf16* __restrict__ corrT) {
  __shared__ unsigned short f1r[128];
  int p = blockIdx.x;
  int b = blockIdx.y;
  int t = threadIdx.x;  // 64
  const unsigned short* f1 = (const unsigned short*)Fp2 + ((long)b * 1024 + p) * 128;
  if (t < 16) *(uint4*)&f1r[t * 8] = *(const uint4*)(f1 + t * 8);
  __syncthreads();
  long rowo = ((long)b * 1024 + p) * 64;
  if (t < 49) {
    int dy = t / 7 - 3, dx = t % 7 - 3;
    int h = p >> 5, w = p & 31;
    int p2 = (((h - dy) & 31) << 5) | ((w - dx) & 31);
    const unsigned short* f2 = (const unsigned short*)Fp2 + ((long)(b + 1) * 1024 + p2) * 128;
    float s = 0.0f;
    for (int c = 0; c < 128; c += 8) {
      union { unsigned short u[8]; uint4 v; } av = { .v = *(const uint4*)&f1r[c] };
      union { unsigned short u[8]; uint4 v; } bv = { .v = *(const uint4*)(f2 + c) };
#pragma unroll
      for (int j = 0; j < 8; ++j) s += shf(av.u[j]) * shf(bv.u[j]);
    }
    corrT[rowo + t] = f2bf(s * 0.08838834764831845f);
  } else {
    corrT[rowo + t] = f2bf(0.0f);
  }
}

// ================= fused row-local transformer segments =================
// wave GEMM tile: 16 rows x 64 cols; A bf16 from LDS/global (stride LDA shorts),
// W fragments direct from global (bf16 or fp32).
template <int KT>
DEV void wtile(const unsigned short* Al, int LDA, const void* W, long woff,
               int ncol0, int isb, int ln, f32x4* acc) {
  int quad = ln >> 4, l16 = ln & 15;
  if (isb) {
    const unsigned short* wb = (const unsigned short*)W + woff + quad * 8;
    for (int kc = 0; kc < KT / 32; ++kc) {
      bf16x8 af = *(const bf16x8*)&Al[l16 * LDA + kc * 32 + quad * 8];
#pragma unroll
      for (int nt = 0; nt < 4; ++nt) {
        bf16x8 wf = *(const bf16x8*)(wb + (long)(ncol0 + nt * 16 + l16) * KT + kc * 32);
        acc[nt] = __builtin_amdgcn_mfma_f32_16x16x32_bf16(af, wf, acc[nt], 0, 0, 0);
      }
    }
  } else {
    const float* wb = (const float*)W + woff + quad * 8;
    for (int kc = 0; kc < KT / 32; ++kc) {
      bf16x8 af = *(const bf16x8*)&Al[l16 * LDA + kc * 32 + quad * 8];
#pragma unroll
      for (int nt = 0; nt < 4; ++nt) {
        const float* wp = wb + (long)(ncol0 + nt * 16 + l16) * KT + kc * 32;
        float4 w0 = *(const float4*)wp;
        float4 w1 = *(const float4*)(wp + 4);
        union { unsigned short u[8]; bf16x8 v; } pk;
        pk.u[0] = bfr(w0.x); pk.u[1] = bfr(w0.y); pk.u[2] = bfr(w0.z); pk.u[3] = bfr(w0.w);
        pk.u[4] = bfr(w1.x); pk.u[5] = bfr(w1.y); pk.u[6] = bfr(w1.z); pk.u[7] = bfr(w1.w);
        acc[nt] = __builtin_amdgcn_mfma_f32_16x16x32_bf16(af, pk.v, acc[nt], 0, 0, 0);
      }
    }
  }
}

// row LayerNorm (16 rows, 256 threads: 16 lanes/row x 12 elems), fp32 src -> bf16 dst
DEV void ln_row(const float* src, int ss, const void* w, long wo,
                const void* b, long bo, int isb, int tid,
                unsigned short* dst, int ds) {
  int row = tid >> 4, j = tid & 15;
  const float* s = src + (long)row * ss + j * 12;
  float a[12];
#pragma unroll
  for (int q = 0; q < 12; ++q) a[q] = s[q];
  float sum = 0.0f;
#pragma unroll
  for (int q = 0; q < 12; ++q) sum += a[q];
#pragma unroll
  for (int o = 1; o < 16; o <<= 1) sum += __shfl_xor(sum, o);
  float mean = sum * (1.0f / 192.0f);
  float vs = 0.0f;
#pragma unroll
  for (int q = 0; q < 12; ++q) { float d = a[q] - mean; vs += d * d; }
#pragma unroll
  for (int o = 1; o < 16; o <<= 1) vs += __shfl_xor(vs, o);
  float rstd = rsqrtf(vs * (1.0f / 192.0f) + 1e-5f);
  unsigned short* d = dst + (long)row * ds + j * 12;
#pragma unroll
  for (int q = 0; q < 12; ++q) {
    long k = j * 12 + q;
    d[q] = bfr((a[q] - mean) * rstd * ldw(w, wo + k, isb) + ldw(b, bo + k, isb));
  }
}

// qkv tail: 9 tiles over 4 waves; writes qkvbb bf16 + vt scatter
DEV void qkv_tail(const unsigned short* tbp, int wv, int ln, int m0, int isb,
                  const void* inw, long o_inw, const void* inb, long o_inb,
                  bf16* qkvbb, bf16* vtb) {
  int quad = ln >> 4, l16 = ln & 15;
  for (int t = wv; t < 9; t += 4) {
    f32x4 acc[4] = {};
    wtile<192>(tbp, 200, inw, o_inw, t * 64, isb, ln, acc);
#pragma unroll
    for (int nt = 0; nt < 4; ++nt) {
      int n = t * 64 + nt * 16 + l16;
#pragma unroll
      for (int r = 0; r < 4; ++r) {
        int m = m0 + quad * 4 + r;
        float v = acc[nt][r] + ldw(inb, o_inb + n, isb);
        qkvbb[(long)m * 576 + n] = f2bf(v);
        if (n >= 384) {
          int hh = (n - 384) / 48, dd = (n - 384) % 48;
          int row = m & 1023, bb2 = m >> 10;
          vtb[((long)(bb2 * 4 + hh) * 48 + dd) * 1024 + row] = f2bf(v);
        }
      }
    }
  }
}

// fused: merge+proj(+res) -> LN2 -> mlp1(gelu) -> mlp2(+res) -> [TAIL1: LN1+qkv | TAIL2: head]
template <int TAIL>
__global__ __launch_bounds__(256, 2) void k_fuse(
    const int* __restrict__ fl, float* __restrict__ x,
    const unsigned short* __restrict__ mop, const float* __restrict__ mml,
    const void* ow, long o_ow, const void* ob, long o_ob,
    const void* ln2w, long o_l2w, const void* ln2b, long o_l2b,
    const void* w1, long o_w1, const void* b1, long o_b1,
    const void* w2, long o_w2, const void* b2, long o_b2,
    const void* ln1w, long o_l1w, const void* ln1b, long o_l1b,
    const void* inw, long o_inw, const void* inb, long o_inb,
    bf16* qkvbb, bf16* vtb,
    const void* hw1, const void* hb1, const void* hw2, const void* hb2,
    float* cur) {
  __shared__ float xs[16][200];
  __shared__ unsigned short tb[16][200];
  __shared__ unsigned short hb[16][776];
  int tid = threadIdx.x, wv = tid >> 6, ln = tid & 63;
  int quad = ln >> 4, l16 = ln & 15;
  int m0 = blockIdx.x * 16;
  int isb = *fl;
  // ---- merge attention partials (wave0: 4 lanes/row, 16 rows) -> tb ----
  if (tid < 64) {
    int row = tid >> 2, j = tid & 3;
    int m = m0 + row;
    int rr = m & 1023, bb = m >> 10;
    long idx[4];
    float ms[4], ls[4];
    float Ms = -1e30f;
#pragma unroll
    for (int s = 0; s < 4; ++s) {
      idx[s] = (((long)s * 2 + bb) * 4 + j) * 1024 + rr;
      ms[s] = mml[idx[s] * 2];
      ls[s] = mml[idx[s] * 2 + 1];
      Ms = fmaxf(Ms, ms[s]);
    }
    float e4[4], L = 0.0f;
#pragma unroll
    for (int s = 0; s < 4; ++s) { e4[s] = __expf(ms[s] - Ms); L += ls[s] * e4[s]; }
    float invL = 1.0f / L;
#pragma unroll
    for (int g = 0; g < 6; ++g) {
      union { unsigned short u[8]; uint4 v; } pk;
#pragma unroll
      for (int e2 = 0; e2 < 8; ++e2) {
        float o = 0.0f;
#pragma unroll
        for (int s = 0; s < 4; ++s) o += shf(mop[idx[s] * 48 + g * 8 + e2]) * e4[s];
        pk.u[e2] = bfr(o * invL);
      }
      *(uint4*)&tb[row][j * 48 + g * 8] = pk.v;
    }
  }
  __syncthreads();
  // ---- out-proj 16x192 + bias + residual -> xs, x ----
  if (wv < 3) {
    f32x4 acc[4] = {};
    wtile<192>(&tb[0][0], 200, ow, o_ow, wv * 64, isb, ln, acc);
#pragma unroll
    for (int nt = 0; nt < 4; ++nt) {
      int n = wv * 64 + nt * 16 + l16;
#pragma unroll
      for (int r = 0; r < 4; ++r) {
        int mrow = quad * 4 + r;
        int m = m0 + mrow;
        float v = acc[nt][r] + ldw(ob, o_ob + n, isb) + x[(long)m * 192 + n];
        x[(long)m * 192 + n] = v;
        xs[mrow][n] = v;
      }
    }
  }
  __syncthreads();
  // ---- LN2 -> tb ----
  ln_row(&xs[0][0], 200, ln2w, o_l2w, ln2b, o_l2b, isb, tid, &tb[0][0], 200);
  __syncthreads();
  // ---- mlp1 16x768 (3 tiles/wave), gelu -> hb ----
  for (int t = wv; t < 12; t += 4) {
    f32x4 acc[4] = {};
    wtile<192>(&tb[0][0], 200, w1, o_w1, t * 64, isb, ln, acc);
#pragma unroll
    for (int nt = 0; nt < 4; ++nt) {
      int n = t * 64 + nt * 16 + l16;
#pragma unroll
      for (int r = 0; r < 4; ++r)
        hb[quad * 4 + r][n] = bfr(gelu_exact(acc[nt][r] + ldw(b1, o_b1 + n, isb)));
    }
  }
  __syncthreads();
  // ---- mlp2 16x192 K=768 + bias + residual -> xs, x (TAIL2: also bf16 copy to tb) ----
  if (wv < 3) {
    f32x4 acc[4] = {};
    wtile<768>(&hb[0][0], 776, w2, o_w2, wv * 64, isb, ln, acc);
#pragma unroll
    for (int nt = 0; nt < 4; ++nt) {
      int n = wv * 64 + nt * 16 + l16;
#pragma unroll
      for (int r = 0; r < 4; ++r) {
        int mrow = quad * 4 + r;
        int m = m0 + mrow;
        float v = acc[nt][r] + ldw(b2, o_b2 + n, isb) + xs[mrow][n];
        x[(long)m * 192 + n] = v;
        xs[mrow][n] = v;
        if constexpr (TAIL == 2) tb[mrow][n] = bfr(v);
      }
    }
  }
  __syncthreads();
  if constexpr (TAIL == 1) {
    ln_row(&xs[0][0], 200, ln1w, o_l1w, ln1b, o_l1b, isb, tid, &tb[0][0], 200);
    __syncthreads();
    qkv_tail(&tb[0][0], wv, ln, m0, isb, inw, o_inw, inb, o_inb, qkvbb, vtb);
  } else if constexpr (TAIL == 2) {
    // head1: gelu(x2 @ hw1^T + hb1) fp32 -> hf (alias hb)
    float* hf = (float*)&hb[0][0];  // [16][200] floats (12.8KB <= 24.8KB)
    if (wv < 3) {
      f32x4 acc[4] = {};
      wtile<192>(&tb[0][0], 200, hw1, 0, wv * 64, isb, ln, acc);
#pragma unroll
      for (int nt = 0; nt < 4; ++nt) {
        int n = wv * 64 + nt * 16 + l16;
#pragma unroll
        for (int r = 0; r < 4; ++r)
          hf[(quad * 4 + r) * 200 + n] = gelu_exact(acc[nt][r] + ldw(hb1, n, isb));
      }
    }
    __syncthreads();
    // head2: 32 dots (16 rows x 2 outs), wave-per-dot
    for (int p = wv; p < 32; p += 4) {
      int row = p >> 1, n = p & 1;
      float s = 0.0f;
#pragma unroll
      for (int q = 0; q < 3; ++q) {
        int j = ln + q * 64;
        s += hf[row * 200 + j] * ldw(hw2, (long)n * 192 + j, isb);
      }
      for (int o = 32; o; o >>= 1) s += __shfl_xor(s, o);
      if (ln == 0) {
        int m = m0 + row;
        int bb2 = m >> 10, pp = m & 1023;
        cur[((long)bb2 * 2 + n) * 1024 + pp] = s + ldw(hb2, n, isb);
      }
    }
  }
}

// fused stage 0: tokenizer GEMM (corrT bf16 @ wtok bf16) -> x, then LN1+qkv
__global__ __launch_bounds__(256, 2) void k_fuse0(
    const int* __restrict__ fl, const bf16* __restrict__ corrTb,
    const bf16* __restrict__ wtok, const void* tok_b,
    float* __restrict__ x,
    const void* ln1w, long o_l1w, const void* ln1b, long o_l1b,
    const void* inw, long o_inw, const void* inb, long o_inb,
    bf16* qkvbb, bf16* vtb) {
  __shared__ float xs[16][200];
  __shared__ unsigned short tb[16][200];
  int tid = threadIdx.x, wv = tid >> 6, ln = tid & 63;
  int quad = ln >> 4, l16 = ln & 15;
  int m0 = blockIdx.x * 16;
  int isb = *fl;
  if (wv < 3) {
    f32x4 acc[4] = {};
    wtile<64>((const unsigned short*)corrTb + (long)m0 * 64, 64, wtok, 0, wv * 64, 1, ln, acc);
#pragma unroll
    for (int nt = 0; nt < 4; ++nt) {
      int n = wv * 64 + nt * 16 + l16;
#pragma unroll
      for (int r = 0; r < 4; ++r) {
        int mrow = quad * 4 + r;
        int m = m0 + mrow;
        float v = acc[nt][r] + ldw(tok_b, n, isb);
        x[(long)m * 192 + n] = v;
        xs[mrow][n] = v;
      }
    }
  }
  __syncthreads();
  ln_row(&xs[0][0], 200, ln1w, o_l1w, ln1b, o_l1b, isb, tid, &tb[0][0], 200);
  __syncthreads();
  qkv_tail(&tb[0][0], wv, ln, m0, isb, inw, o_inw, inb, o_inb, qkvbb, vtb);
}

// fused LN1+qkv only (after EMA)
__global__ __launch_bounds__(256, 2) void k_fuseA(
    const int* __restrict__ fl, const float* __restrict__ x,
    const void* ln1w, long o_l1w, const void* ln1b, long o_l1b,
    const void* inw, long o_inw, const void* inb, long o_inb,
    bf16* qkvbb, bf16* vtb) {
  __shared__ unsigned short tb[16][200];
  int tid = threadIdx.x, wv = tid >> 6, ln = tid & 63;
  int m0 = blockIdx.x * 16;
  int isb = *fl;
  ln_row(x + (long)m0 * 192, 192, ln1w, o_l1w, ln1b, o_l1b, isb, tid, &tb[0][0], 200);
  __syncthreads();
  qkv_tail(&tb[0][0], wv, ln, m0, isb, inw, o_inw, inb, o_inb, qkvbb, vtb);
}

// ---------------- MFMA flash attention, split-K ----------------
__global__ __launch_bounds__(256) void k_attn_mfma(const bf16* __restrict__ qkv,
                                                   const bf16* __restrict__ vt,
                                                   unsigned short* __restrict__ opart,
                                                   float* __restrict__ ml) {
  __shared__ unsigned short Qs[64][72];
  __shared__ unsigned short Ks[64][72];
  __shared__ unsigned short Vs[48][72];
  __shared__ unsigned short Ps[64][72];
  int tid = threadIdx.x;
  int wv = tid >> 6, ln = tid & 63, quad = ln >> 4, l16 = ln & 15;
  int h = blockIdx.y, b = blockIdx.z;
  int qt = blockIdx.x >> 2, s = blockIdx.x & 3;
  int q0 = qt * 64;
  const unsigned short* qp = (const unsigned short*)qkv + (long)b * 1024 * 576;
  const unsigned short* vp = (const unsigned short*)vt + ((long)(b * 4 + h) * 48) * 1024;
  for (int i = tid; i < 384; i += 256) {
    int r = i / 6, c = i % 6;
    *(uint4*)&Qs[r][c * 8] = *(const uint4*)(qp + (long)(q0 + r) * 576 + h * 48 + c * 8);
  }
  for (int i = tid; i < 128; i += 256) {
    int r = i >> 1, c = 6 + (i & 1);
    uint4 z = {0, 0, 0, 0};
    *(uint4*)&Qs[r][c * 8] = z;
  }
  float m[4] = {-1e30f, -1e30f, -1e30f, -1e30f};
  float l[4] = {0.0f, 0.0f, 0.0f, 0.0f};
  f32x4 accO[3] = {};
  const float SC = 0.14433756729740643f;
  for (int kc = s * 4; kc < s * 4 + 4; ++kc) {
    int k0 = kc * 64;
    for (int i = tid; i < 384; i += 256) {
      int r = i / 6, c = i % 6;
      *(uint4*)&Ks[r][c * 8] = *(const uint4*)(qp + (long)(k0 + r) * 576 + 192 + h * 48 + c * 8);
    }
    for (int i = tid; i < 128; i += 256) {
      int r = i >> 1, c = 6 + (i & 1);
      uint4 z = {0, 0, 0, 0};
      *(uint4*)&Ks[r][c * 8] = z;
    }
    for (int i = tid; i < 384; i += 256) {
      int d = i >> 3, c = i & 7;
      *(uint4*)&Vs[d][c * 8] = *(const uint4*)(vp + (long)d * 1024 + k0 + c * 8);
    }
    __syncthreads();
    f32x4 accS[4] = {};
    bf16x8 a0 = *(const bf16x8*)&Qs[wv * 16 + l16][quad * 8];
    bf16x8 a1 = *(const bf16x8*)&Qs[wv * 16 + l16][32 + quad * 8];
#pragma unroll
    for (int ct = 0; ct < 4; ++ct) {
      bf16x8 b0 = *(const bf16x8*)&Ks[ct * 16 + l16][quad * 8];
      bf16x8 b1 = *(const bf16x8*)&Ks[ct * 16 + l16][32 + quad * 8];
      accS[ct] = __builtin_amdgcn_mfma_f32_16x16x32_bf16(a0, b0, accS[ct], 0, 0, 0);
      accS[ct] = __builtin_amdgcn_mfma_f32_16x16x32_bf16(a1, b1, accS[ct], 0, 0, 0);
    }
#pragma unroll
    for (int r = 0; r < 4; ++r) {
      float s0 = accS[0][r] * SC, s1 = accS[1][r] * SC;
      float s2 = accS[2][r] * SC, s3 = accS[3][r] * SC;
      float mx = fmaxf(fmaxf(s0, s1), fmaxf(s2, s3));
      for (int o = 8; o; o >>= 1) mx = fmaxf(mx, __shfl_xor(mx, o));
      float mn = fmaxf(m[r], mx);
      float alpha = __expf(m[r] - mn);
      float p0 = __expf(s0 - mn), p1 = __expf(s1 - mn);
      float p2 = __expf(s2 - mn), p3 = __expf(s3 - mn);
      float rs = p0 + p1 + p2 + p3;
      for (int o = 8; o; o >>= 1) rs += __shfl_xor(rs, o);
      m[r] = mn;
      l[r] = l[r] * alpha + rs;
      accO[0][r] *= alpha; accO[1][r] *= alpha; accO[2][r] *= alpha;
      int prow = wv * 16 + quad * 4 + r;
      Ps[prow][l16]      = bfr(p0);
      Ps[prow][16 + l16] = bfr(p1);
      Ps[prow][32 + l16] = bfr(p2);
      Ps[prow][48 + l16] = bfr(p3);
    }
    bf16x8 pf0 = *(const bf16x8*)&Ps[wv * 16 + l16][quad * 8];
    bf16x8 pf1 = *(const bf16x8*)&Ps[wv * 16 + l16][32 + quad * 8];
#pragma unroll
    for (int ct = 0; ct < 3; ++ct) {
      bf16x8 v0 = *(const bf16x8*)&Vs[ct * 16 + l16][quad * 8];
      bf16x8 v1 = *(const bf16x8*)&Vs[ct * 16 + l16][32 + quad * 8];
      accO[ct] = __builtin_amdgcn_mfma_f32_16x16x32_bf16(pf0, v0, accO[ct], 0, 0, 0);
      accO[ct] = __builtin_amdgcn_mfma_f32_16x16x32_bf16(pf1, v1, accO[ct], 0, 0, 0);
    }
    __syncthreads();
  }
  long base = (((long)s * 2 + b) * 4 + h) * 1024;
#pragma unroll
  for (int r = 0; r < 4; ++r) {
    int row = q0 + wv * 16 + quad * 4 + r;
#pragma unroll
    for (int ct = 0; ct < 3; ++ct)
      opart[(base + row) * 48 + ct * 16 + l16] = bfr(accO[ct][r]);
    if (l16 == 0) {
      ml[(base + row) * 2]     = m[r];
      ml[(base + row) * 2 + 1] = l[r];
    }
  }
}

// ---------------- EMA / upsample / out ----------------
__global__ void k_ema(float* __restrict__ x) {
  int i = blockIdx.x * blockDim.x + threadIdx.x;
  if (i < 196608) x[196608 + i] = 0.8f * x[196608 + i] + 0.2f * x[i];
}

__global__ void k_upsample(const float* __restrict__ in, float* __restrict__ out) {
  int i = blockIdx.x * blockDim.x + threadIdx.x;
  if (i >= 2 * 2 * 64 * 64) return;
  int p = i & 4095;
  int bc = i >> 12;
  int oy = p >> 6, ox = p & 63;
  float sx = ox * (31.0f / 63.0f), sy = oy * (31.0f / 63.0f);
  int x0 = (int)sx, y0 = (int)sy;
  int x1 = min(x0 + 1, 31), y1 = min(y0 + 1, 31);
  float wx = sx - x0, wy = sy - y0;
  const float* ic = in + (long)bc * 1024;
  out[i] = ic[y0 * 32 + x0] * (1 - wx) * (1 - wy) + ic[y0 * 32 + x1] * wx * (1 - wy)
         + ic[y1 * 32 + x0] * (1 - wx) * wy      + ic[y1 * 32 + x1] * wx * wy;
}

__global__ void k_out(const float* __restrict__ cur2, void* __restrict__ out,
                      const int* __restrict__ fl) {
  int isb = *fl;
  int i = blockIdx.x * blockDim.x + threadIdx.x;
  if (i < 16384) {
    if (isb) ((bf16*)out)[i] = f2bf(cur2[i]);
    else ((float*)out)[i] = cur2[i];
  }
}

extern "C" void kernel_launch(void* const* d_in, const int* in_sizes, int n_in,
                              void* d_out, int out_size, void* d_ws, size_t ws_size,
                              hipStream_t stream) {
  const void* feats_l1 = d_in[0];
  const void* feats_l2 = d_in[1];
  const void* tok_w = d_in[3];
  const void* tok_b = d_in[4];
  const void* lcm_ln1_w = d_in[5];
  const void* lcm_ln1_b = d_in[6];
  const void* lcm_in_w  = d_in[7];
  const void* lcm_in_b  = d_in[8];
  const void* lcm_out_w = d_in[9];
  const void* lcm_out_b = d_in[10];
  const void* lcm_ln2_w = d_in[11];
  const void* lcm_ln2_b = d_in[12];
  const void* lcm_mlp_w1 = d_in[13];
  const void* lcm_mlp_b1 = d_in[14];
  const void* lcm_mlp_w2 = d_in[15];
  const void* lcm_mlp_b2 = d_in[16];
  const void* gtr_ln1_w = d_in[17];
  const void* gtr_ln1_b = d_in[18];
  const void* gtr_in_w  = d_in[19];
  const void* gtr_in_b  = d_in[20];
  const void* gtr_out_w = d_in[21];
  const void* gtr_out_b = d_in[22];
  const void* gtr_ln2_w = d_in[23];
  const void* gtr_ln2_b = d_in[24];
  const void* gtr_mlp_w1 = d_in[25];
  const void* gtr_mlp_b1 = d_in[26];
  const void* gtr_mlp_w2 = d_in[27];
  const void* gtr_mlp_b2 = d_in[28];
  const void* head_w1 = d_in[29];
  const void* head_b1 = d_in[30];
  const void* head_w2 = d_in[31];
  const void* head_b2 = d_in[32];
  const void* ref1_w1 = d_in[33];
  const void* ref1_b1 = d_in[34];
  const void* ref1_w2 = d_in[35];
  const void* ref1_b2 = d_in[36];
  const void* ref0_w1 = d_in[37];
  const void* ref0_b1 = d_in[38];
  const void* ref0_w2 = d_in[39];
  const void* ref0_b2 = d_in[40];
  (void)ws_size; (void)n_in; (void)in_sizes; (void)out_size;

  // ---- workspace layout (f-eq units; ~16.8 MB) ----
  int* flag = (int*)d_ws;
  float* wsf = (float*)d_ws;
  float* F2   = wsf + 16;             // 393216 (spare)
  float* rA   = F2 + 393216;          // 786432 : opart bf16
  float* rX   = rA + 786432;          // 393216 : residual x
  float* rT   = rX + 393216;          // 393216 : corrT bf16 | mid0packed
  float* rY   = rT + 393216;          // 393216 : mlbuf | mid1packed
  float* big  = rY + 393216;          // 1572864: qkv/vt [0,851968) | Fp2+Fp1 tail
  float* fv   = big + 1572864;        // 4096 (unused)
  float* cur  = fv + 4096;            // 4096
  float* cur2 = cur + 4096;           // 16384
  float* cb1a = cur2 + 16384;         // 128
  float* cb1b = cb1a + 128;           // 16
  float* cb0a = cb1b + 16;            // 64
  float* cb0b = cb0a + 64;            // 16
  bf16* wtok  = (bf16*)(cb0b + 16);   // 12288 shorts
  float* wpk  = cb0b + 16 + 6144;
  bf16* w1p1 = (bf16*)wpk;            // 331776 shorts
  bf16* w1p2 = (bf16*)(wpk + 165888); // 18432 shorts
  bf16* w0p1 = (bf16*)(wpk + 175104); // 92160 shorts
  bf16* w0p2 = (bf16*)(wpk + 221184); // 9216 shorts

  float* x = rX;
  bf16* corrTb = (bf16*)rT;                     // [2048][64] bf16 (dead before decoder)
  bf16* qkvbb  = (bf16*)big;
  bf16* vtb    = (bf16*)(big + 655360);
  unsigned short* opart = (unsigned short*)rA;  // [4][2][4][1024][48] bf16
  float* mlbuf = rY;                            // [4][2][4][1024][2] fp32
  bf16* mid0p = (bf16*)rT;
  bf16* mid1p = (bf16*)rY;
  bf16* Fp2   = (bf16*)(big + 851968);   // [3][1024][128]
  bf16* Fp1   = (bf16*)(big + 1048576);  // [3][4096][64]

  k_detect<<<1, 256, 0, stream>>>((const unsigned short*)feats_l1, flag);
  k_cvt<<<1, 256, 0, stream>>>(ref1_b1, cb1a, 128, flag);
  k_cvt<<<1, 256, 0, stream>>>(ref1_b2, cb1b, 2, flag);
  k_cvt<<<1, 256, 0, stream>>>(ref0_b1, cb0a, 64, flag);
  k_cvt<<<1, 256, 0, stream>>>(ref0_b2, cb0b, 2, flag);
  k_padtokw<<<48, 256, 0, stream>>>(tok_w, wtok, flag);
  k_packw<<<1296, 256, 0, stream>>>(ref1_w1, w1p1, 128, 128, 258, 128, 288, 331776, flag);
  k_packw<<<72, 256, 0, stream>>>(ref1_w2, w1p2, 2, 128, 128, 16, 128, 18432, flag);
  k_packw<<<360, 256, 0, stream>>>(ref0_w1, w0p1, 64, 64, 130, 64, 160, 92160, flag);
  k_packw<<<36, 256, 0, stream>>>(ref0_w2, w0p2, 2, 64, 64, 16, 64, 9216, flag);
  k_trans_feats<<<192, 256, 0, stream>>>(feats_l2, Fp2, 3, 128, 1024, flag);
  k_trans_feats<<<384, 256, 0, stream>>>(feats_l1, Fp1, 3, 64, 4096, flag);

  // ---- tokens: corr then fused tok-GEMM + LN1 + qkv ----
  k_corr<<<dim3(1024, 2), 64, 0, stream>>>(Fp2, corrTb);
  k_fuse0<<<128, 256, 0, stream>>>(flag, corrTb, wtok, tok_b, x,
                                   lcm_ln1_w, 0, lcm_ln1_b, 0,
                                   lcm_in_w, 0, lcm_in_b, 0, qkvbb, vtb);

  for (int i = 0; i < 8; ++i) {
    k_attn_mfma<<<dim3(64, 4, 2), 256, 0, stream>>>(qkvbb, vtb, opart, mlbuf);
    bool lcm = i < 6;
    long ii = lcm ? i : (i - 6);
    const void* ow  = lcm ? lcm_out_w  : gtr_out_w;
    const void* ob  = lcm ? lcm_out_b  : gtr_out_b;
    const void* l2w = lcm ? lcm_ln2_w  : gtr_ln2_w;
    const void* l2b = lcm ? lcm_ln2_b  : gtr_ln2_b;
    const void* w1  = lcm ? lcm_mlp_w1 : gtr_mlp_w1;
    const void* b1  = lcm ? lcm_mlp_b1 : gtr_mlp_b1;
    const void* w2  = lcm ? lcm_mlp_w2 : gtr_mlp_w2;
    const void* b2  = lcm ? lcm_mlp_b2 : gtr_mlp_b2;
    long o5 = ii * 36864, o6 = ii * 192, o7 = ii * 192, o8 = ii * 192;
    long o9 = ii * 147456, o10 = ii * 768, o11 = ii * 147456, o12 = ii * 192;
    if (i < 5) {
      long nx = i + 1;
      k_fuse<1><<<128, 256, 0, stream>>>(
          flag, x, opart, mlbuf, ow, o5, ob, o6, l2w, o7, l2b, o8,
          w1, o9, b1, o10, w2, o11, b2, o12,
          lcm_ln1_w, nx * 192, lcm_ln1_b, nx * 192,
          lcm_in_w, nx * 110592, lcm_in_b, nx * 576,
          qkvbb, vtb, nullptr, nullptr, nullptr, nullptr, nullptr);
    } else if (i == 5) {
      k_fuse<0><<<128, 256, 0, stream>>>(
          flag, x, opart, mlbuf, ow, o5, ob, o6, l2w, o7, l2b, o8,
          w1, o9, b1, o10, w2, o11, b2, o12,
          nullptr, 0, nullptr, 0, nullptr, 0, nullptr, 0,
          nullptr, nullptr, nullptr, nullptr, nullptr, nullptr, nullptr);
      k_ema<<<768, 256, 0, stream>>>(x);
      k_fuseA<<<128, 256, 0, stream>>>(flag, x, gtr_ln1_w, 0, gtr_ln1_b, 0,
                                       gtr_in_w, 0, gtr_in_b, 0, qkvbb, vtb);
    } else if (i == 6) {
      k_fuse<1><<<128, 256, 0, stream>>>(
          flag, x, opart, mlbuf, ow, o5, ob, o6, l2w, o7, l2b, o8,
          w1, o9, b1, o10, w2, o11, b2, o12,
          gtr_ln1_w, 192, gtr_ln1_b, 192, gtr_in_w, 110592, gtr_in_b, 576,
          qkvbb, vtb, nullptr, nullptr, nullptr, nullptr, nullptr);
    } else {
      k_fuse<2><<<128, 256, 0, stream>>>(
          flag, x, opart, mlbuf, ow, o5, ob, o6, l2w, o7, l2b, o8,
          w1, o9, b1, o10, w2, o11, b2, o12,
          nullptr, 0, nullptr, 0, nullptr, 0, nullptr, 0,
          nullptr, nullptr, head_w1, head_b1, head_w2, head_b2, cur);
    }
  }

  // ---- decoder prep: zero mid buffers (borders must stay 0) ----
  k_zerosh<<<768, 256, 0, stream>>>((unsigned short*)rT, 196608);

  // ---- decoder level 1 (32x32): C=128, ICP=288, OC=128 ----
  for (int it = 0; it < 4; ++it) {
    k_conv1d<128, 288, 128, 32, 5><<<dim3(8, 64, 2), 64, 0, stream>>>(
        Fp2, cur, w1p1, cb1a, mid1p);
    k_conv2_dot<128, 32, 5><<<512, 256, 0, stream>>>(mid1p, w1p2, cb1b, cur);
  }
  k_upsample<<<64, 256, 0, stream>>>(cur, cur2);

  // ---- decoder level 0 (64x64): C=64, ICP=160, OC=64 ----
  for (int it = 0; it < 4; ++it) {
    k_conv1d<64, 160, 64, 64, 6><<<dim3(4, 256, 2), 64, 0, stream>>>(
        Fp1, cur2, w0p1, cb0a, mid0p);
    k_conv2_dot<64, 64, 6><<<2048, 256, 0, stream>>>(mid0p, w0p2, cb0b, cur2);
  }

  k_out<<<64, 256, 0, stream>>>(cur2, d_out, flag);
}

// Round 12
// 1005.264 us; speedup vs baseline: 4.6095x; 1.1330x over previous
//
#include <hip/hip_runtime.h>
#include <hip/hip_bf16.h>

typedef __hip_bfloat16 bf16;
typedef short bf16x8 __attribute__((ext_vector_type(8)));
typedef float f32x4 __attribute__((ext_vector_type(4)));

#define DEV __device__ __forceinline__

DEV float bf2f(bf16 v) { return __bfloat162float(v); }
DEV bf16 f2bf(float v) { return __float2bfloat16(v); }
DEV unsigned short bfr(float f) {
  bf16 h = __float2bfloat16(f);
  return *reinterpret_cast<unsigned short*>(&h);
}
DEV float shf(unsigned short u) {
  unsigned int x = ((unsigned int)u) << 16;
  return *reinterpret_cast<float*>(&x);
}
DEV float gelu_exact(float x) { return 0.5f * x * (1.0f + erff(x * 0.70710678118654752f)); }

DEV float ldw(const void* p, long i, int isb) {
  return isb ? __bfloat162float(((const bf16*)p)[i]) : ((const float*)p)[i];
}

// bilinear upsample 32x32 -> 64x64 read (identical formula to the old k_upsample)
DEV float ups_read(const float* __restrict__ cur, int b, int c, int oy, int ox) {
  float sx = ox * (31.0f / 63.0f), sy = oy * (31.0f / 63.0f);
  int x0 = (int)sx, y0 = (int)sy;
  int x1 = min(x0 + 1, 31), y1 = min(y0 + 1, 31);
  float wx = sx - x0, wy = sy - y0;
  const float* ic = cur + (long)(b * 2 + c) * 1024;
  return ic[y0 * 32 + x0] * (1 - wx) * (1 - wy) + ic[y0 * 32 + x1] * wx * (1 - wy)
       + ic[y1 * 32 + x0] * (1 - wx) * wy      + ic[y1 * 32 + x1] * wx * wy;
}

// ---------------- dtype detection + flag constants ----------------
__global__ void k_detect(const unsigned short* __restrict__ u, int* __restrict__ flag) {
  __shared__ int bad;
  if (threadIdx.x == 0) bad = 0;
  __syncthreads();
  for (int i = threadIdx.x; i < 8192; i += 256) {
    int expo = (u[i] >> 7) & 0xFF;
    if (expo >= 138) atomicOr(&bad, 1);
  }
  __syncthreads();
  if (threadIdx.x == 0) *flag = bad ? 0 : 1;
}
__global__ void k_setone(int* p) { *p = 1; }

// ---------------- convert (bf16|fp32) -> fp32 ----------------
__global__ void k_cvt(const void* __restrict__ s, float* __restrict__ d, int n,
                      const int* __restrict__ fl) {
  int isb = *fl;
  int i = blockIdx.x * blockDim.x + threadIdx.x;
  if (i < n) d[i] = ldw(s, i, isb);
}

__global__ void k_zerosh(unsigned short* __restrict__ p, int n8) {
  int i = blockIdx.x * blockDim.x + threadIdx.x;
  if (i < n8) { uint4 z = {0, 0, 0, 0}; *(uint4*)(p + (long)i * 8) = z; }
}

// tokenizer weight [192][49] (at element offset 9408) -> bf16 [192][64] zero-padded
__global__ void k_padtokw(const void* __restrict__ tw, bf16* __restrict__ dst,
                          const int* __restrict__ fl) {
  int isb = *fl;
  int i = blockIdx.x * blockDim.x + threadIdx.x;
  if (i >= 12288) return;
  int n = i >> 6, k = i & 63;
  float v = (k < 49) ? ldw(tw, 9408 + (long)n * 49 + k, isb) : 0.0f;
  dst[i] = f2bf(v);
}

// conv weight pack: dst[s][np][icp] bf16 from src [OC][ICT][9]
__global__ void k_packw(const void* __restrict__ src, bf16* __restrict__ dst,
                        int OC, int C, int ICT, int NP, int ICP, int n,
                        const int* __restrict__ fl) {
  int isb = *fl;
  int i = blockIdx.x * blockDim.x + threadIdx.x;
  if (i >= n) return;
  int s = i / (NP * ICP);
  int r = i - s * NP * ICP;
  int oc = r / ICP, icp = r - oc * ICP;
  float v = 0.0f;
  if (oc < OC) {
    int ic = -1;
    if (icp < C) ic = icp;
    else if (icp < 2 * C) ic = icp - C + C + 2;
    else if (icp < 2 * C + 2) ic = icp - 2 * C + C;
    if (ic >= 0 && ic < ICT) v = ldw(src, ((long)oc * ICT + ic) * 9 + s, isb);
  }
  dst[i] = f2bf(v);
}

// feats [F][C][HW] -> pixel-major bf16 [F][HW][C]
__global__ void k_trans_feats(const void* __restrict__ in, bf16* __restrict__ Fp,
                              int F, int C, int HW, const int* __restrict__ fl) {
  int isb = *fl;
  int cpg = C >> 3;
  int n = F * HW * cpg;
  int i = blockIdx.x * blockDim.x + threadIdx.x;
  if (i >= n) return;
  int p = i % HW;
  int rem = i / HW;
  int c8 = rem % cpg;
  int f = rem / cpg;
  long base = (long)f * C * HW + (long)(c8 * 8) * HW + p;
  union { unsigned short u[8]; uint4 v; } pk;
#pragma unroll
  for (int j = 0; j < 8; ++j) pk.u[j] = bfr(ldw(in, base + (long)j * HW, isb));
  *(uint4*)((unsigned short*)Fp + ((long)f * HW + p) * C + c8 * 8) = pk.v;
}

// ---------------- decoder conv1: single-wave, barrier-free, spill-free ----------------
// UPS=1: flow points to the coarse 32x32 field; upsample computed inline.
template <int C, int ICP, int NP, int WW, int LGW, int UPS>
__global__ __launch_bounds__(64, 2) void k_conv1d(
    const bf16* __restrict__ Fp, const float* __restrict__ flow,
    const bf16* __restrict__ Wp, const float* __restrict__ bias,
    bf16* __restrict__ out) {
  constexpr int HH = WW, HW = WW * WW;
  constexpr int ACW = 18, APX = 54;
  constexpr int NK = ICP / 32;
  __shared__ unsigned short As[APX][40];
  __shared__ int pofs[APX];
  __shared__ int doff[APX][4];
  __shared__ float dwt[APX][4];
  __shared__ float ffl[APX][2];
  int ln = threadIdx.x;
  int quad = ln >> 4, l16 = ln & 15;
  int n0 = blockIdx.x * 16, m0 = blockIdx.y * 16, b = blockIdx.z;
  int py0 = m0 >> LGW, px0 = m0 & (WW - 1);
  const unsigned short* fcur = (const unsigned short*)Fp + (long)b * HW * C;
  const unsigned short* fnxt = (const unsigned short*)Fp + (long)(b + 1) * HW * C;
  const float* fl = flow + (UPS ? 0 : (long)b * 2 * HW);
  if (ln < APX) {
    int sr = ln / ACW, sc = ln - sr * ACW;
    int py = py0 + sr - 1, px = px0 + sc - 1;
    bool in = py >= 0 && py < HH && px >= 0 && px < WW;
    int p = in ? (py * WW + px) : 0;
    pofs[ln] = in ? p * C : -1;
    float fx = 0.0f, fy = 0.0f;
    if (in) {
      if constexpr (UPS) {
        fx = ups_read(flow, b, 0, py, px);
        fy = ups_read(flow, b, 1, py, px);
      } else {
        fx = fl[p];
        fy = fl[HW + p];
      }
    }
    float x = fminf(fmaxf((float)px + fx, 0.0f), (float)(WW - 1));
    float y = fminf(fmaxf((float)py + fy, 0.0f), (float)(HH - 1));
    int x0 = (int)floorf(x), y0 = (int)floorf(y);
    int x1 = min(x0 + 1, WW - 1), y1 = min(y0 + 1, HH - 1);
    float wx = x - (float)x0, wy = y - (float)y0;
    dwt[ln][0] = in ? (1 - wx) * (1 - wy) : 0.0f;
    dwt[ln][1] = in ? wx * (1 - wy) : 0.0f;
    dwt[ln][2] = in ? (1 - wx) * wy : 0.0f;
    dwt[ln][3] = in ? wx * wy : 0.0f;
    doff[ln][0] = (y0 * WW + x0) * C; doff[ln][1] = (y0 * WW + x1) * C;
    doff[ln][2] = (y1 * WW + x0) * C; doff[ln][3] = (y1 * WW + x1) * C;
    ffl[ln][0] = in ? fx : 0.0f; ffl[ln][1] = in ? fy : 0.0f;
  }
  const unsigned short* wrow = (const unsigned short*)Wp + (long)(n0 + l16) * ICP + quad * 8;
  f32x4 ac0 = {}, ac1 = {}, ac2 = {};
  for (int kc = 0; kc < NK; ++kc) {
    int chb = kc * 32;
    if (chb < C) {
      uint4 arg[4];
#pragma unroll
      for (int j = 0; j < 4; ++j) {
        int idx = ln + j * 64;
        if (idx < APX * 4) {
          int ap = idx >> 2, c4 = idx & 3;
          int po = pofs[ap];
          uint4 z = {0, 0, 0, 0};
          arg[j] = (po >= 0) ? *(const uint4*)(fcur + po + chb + c4 * 8) : z;
        }
      }
#pragma unroll
      for (int j = 0; j < 4; ++j) {
        int idx = ln + j * 64;
        if (idx < APX * 4) {
          int ap = idx >> 2, c4 = idx & 3;
          *(uint4*)&As[ap][c4 * 8] = arg[j];
        }
      }
    } else if (chb < 2 * C) {
#pragma unroll
      for (int j = 0; j < 4; ++j) {
        int idx = ln + j * 64;
        if (idx < APX * 4) {
          int ap = idx >> 2, c4 = idx & 3;
          int c = chb - C + c4 * 8;
          uint4 v0 = *(const uint4*)(fnxt + doff[ap][0] + c);
          uint4 v1 = *(const uint4*)(fnxt + doff[ap][1] + c);
          uint4 v2 = *(const uint4*)(fnxt + doff[ap][2] + c);
          uint4 v3 = *(const uint4*)(fnxt + doff[ap][3] + c);
          float q0 = dwt[ap][0], q1 = dwt[ap][1], q2 = dwt[ap][2], q3 = dwt[ap][3];
          union { unsigned short u[8]; uint4 v; } a0 = {.v = v0}, a1 = {.v = v1},
                                                  a2 = {.v = v2}, a3 = {.v = v3}, o;
#pragma unroll
          for (int e = 0; e < 8; ++e)
            o.u[e] = bfr(shf(a0.u[e]) * q0 + shf(a1.u[e]) * q1 +
                         shf(a2.u[e]) * q2 + shf(a3.u[e]) * q3);
          *(uint4*)&As[ap][c4 * 8] = o.v;
        }
      }
    } else {
#pragma unroll
      for (int j = 0; j < 4; ++j) {
        int idx = ln + j * 64;
        if (idx < APX * 4) {
          int ap = idx >> 2, c4 = idx & 3;
          union { unsigned short u[8]; uint4 v; } o = { .v = {0, 0, 0, 0} };
          if (c4 == 0) { o.u[0] = bfr(ffl[ap][0]); o.u[1] = bfr(ffl[ap][1]); }
          *(uint4*)&As[ap][c4 * 8] = o.v;
        }
      }
    }
#pragma unroll
    for (int s = 0; s < 9; ++s) {
      int ky = s / 3, kx = s - ky * 3;
      bf16x8 af = *(const bf16x8*)&As[ky * ACW + l16 + kx][quad * 8];
      bf16x8 wf = *(const bf16x8*)(wrow + (long)s * NP * ICP + chb);
      if (s % 3 == 0)      ac0 = __builtin_amdgcn_mfma_f32_16x16x32_bf16(af, wf, ac0, 0, 0, 0);
      else if (s % 3 == 1) ac1 = __builtin_amdgcn_mfma_f32_16x16x32_bf16(af, wf, ac1, 0, 0, 0);
      else                 ac2 = __builtin_amdgcn_mfma_f32_16x16x32_bf16(af, wf, ac2, 0, 0, 0);
    }
  }
  int n = n0 + l16;
  float bv = bias[n];
  long rowbase = (long)b * (HH + 2) * (WW + 2) + (long)(py0 + 1) * (WW + 2);
#pragma unroll
  for (int r = 0; r < 4; ++r) {
    int px = px0 + quad * 4 + r;
    float v = gelu_exact(ac0[r] + ac1[r] + ac2[r] + bv);
    ((unsigned short*)out)[(rowbase + px + 1) * NP + n] = bfr(v);
  }
}

// ---------------- decoder conv2: wave-per-pixel dual dot (N=2, K=9*C) ----------------
// UPS=1: residual comes from inline upsample of `coarse`. FIN=1: also writes d_out.
template <int C, int WW, int LGW, int UPS, int FIN>
__global__ __launch_bounds__(256) void k_conv2_dot(
    const bf16* __restrict__ mid, const bf16* __restrict__ Wq,
    const float* __restrict__ bias, float* __restrict__ cur,
    const float* __restrict__ coarse, void* __restrict__ dout,
    const int* __restrict__ flg) {
  constexpr int HH = WW;
  constexpr int HW = HH * WW;
  constexpr int Wp2 = WW + 2;
  constexpr int CPL = C / 64;
  int tid = threadIdx.x, wv = tid >> 6, ln = tid & 63;
  int gw = blockIdx.x * 4 + wv;
  int b = gw >> (2 * LGW);
  int p = gw & (HW - 1);
  int py = p >> LGW, px = p & (WW - 1);
  float r0, r1;
  if constexpr (UPS) {
    r0 = ups_read(coarse, b, 0, py, px);
    r1 = ups_read(coarse, b, 1, py, px);
  } else {
    r0 = cur[((long)b * 2 + 0) * HW + p];
    r1 = cur[((long)b * 2 + 1) * HW + p];
  }
  float b0 = bias[0], b1 = bias[1];
  const unsigned short* base = (const unsigned short*)mid +
      ((long)b * (HH + 2) * Wp2 + (long)py * Wp2 + px) * C + ln * CPL;
  const unsigned short* wb = (const unsigned short*)Wq + ln * CPL;
  float s0 = 0.0f, s1 = 0.0f;
#pragma unroll
  for (int t = 0; t < 9; ++t) {
    int dy = t / 3, dx = t - dy * 3;
    const unsigned short* ar = base + ((long)dy * Wp2 + dx) * C;
    const unsigned short* w0r = wb + (long)(t * 16 + 0) * C;
    const unsigned short* w1r = wb + (long)(t * 16 + 1) * C;
    if (CPL == 2) {
      unsigned int a = *(const unsigned int*)ar;
      unsigned int q0 = *(const unsigned int*)w0r;
      unsigned int q1 = *(const unsigned int*)w1r;
      float a0 = shf((unsigned short)a), a1 = shf((unsigned short)(a >> 16));
      s0 += a0 * shf((unsigned short)q0) + a1 * shf((unsigned short)(q0 >> 16));
      s1 += a0 * shf((unsigned short)q1) + a1 * shf((unsigned short)(q1 >> 16));
    } else {
      float a0 = shf(ar[0]);
      s0 += a0 * shf(w0r[0]);
      s1 += a0 * shf(w1r[0]);
    }
  }
#pragma unroll
  for (int o = 32; o; o >>= 1) { s0 += __shfl_xor(s0, o); s1 += __shfl_xor(s1, o); }
  if (ln == 0) {
    float v0 = s0 + b0 + r0;
    float v1 = s1 + b1 + r1;
    long o0 = ((long)b * 2 + 0) * HW + p;
    long o1 = ((long)b * 2 + 1) * HW + p;
    cur[o0] = v0;
    cur[o1] = v1;
    if constexpr (FIN) {
      int isb2 = *flg;
      if (isb2) {
        ((bf16*)dout)[o0] = f2bf(v0);
        ((bf16*)dout)[o1] = f2bf(v1);
      } else {
        ((float*)dout)[o0] = v0;
        ((float*)dout)[o1] = v1;
      }
    }
  }
}

// ---------------- local correlation ----------------
__global__ void k_corr(const bf16* __restrict__ Fp2, bf16* __restrict__ corrT) {
  __shared__ unsigned short f1r[128];
  int p = blockIdx.x;
  int b = blockIdx.y;
  int t = threadIdx.x;  // 64
  const unsigned short* f1 = (const unsigned short*)Fp2 + ((long)b * 1024 + p) * 128;
  if (t < 16) *(uint4*)&f1r[t * 8] = *(const uint4*)(f1 + t * 8);
  __syncthreads();
  long rowo = ((long)b * 1024 + p) * 64;
  if (t < 49) {
    int dy = t / 7 - 3, dx = t % 7 - 3;
    int h = p >> 5, w = p & 31;
    int p2 = (((h - dy) & 31) << 5) | ((w - dx) & 31);
    const unsigned short* f2 = (const unsigned short*)Fp2 + ((long)(b + 1) * 1024 + p2) * 128;
    float s = 0.0f;
    for (int c = 0; c < 128; c += 8) {
      union { unsigned short u[8]; uint4 v; } av = { .v = *(const uint4*)&f1r[c] };
      union { unsigned short u[8]; uint4 v; } bv = { .v = *(const uint4*)(f2 + c) };
#pragma unroll
      for (int j = 0; j < 8; ++j) s += shf(av.u[j]) * shf(bv.u[j]);
    }
    corrT[rowo + t] = f2bf(s * 0.08838834764831845f);
  } else {
    corrT[rowo + t] = f2bf(0.0f);
  }
}

// ---------------- single-wave barrier-free MFMA GEMM (transformer) ----------------
// One wave per block, 16 rows x (16*NTW) cols. No __syncthreads. W fragments (and bf16
// A fragments) loaded directly from global (L2-resident). AMODE 2/3 stage the computed
// A-row tile through a private per-wave LDS buffer (within-wave ordering).
// AMODE: 0 = fp32 A; 1 = bf16 A; 2 = fused split-K attention merge; 3 = fused LayerNorm.
template <int KT, int NTW, int ACT, bool HASRES, int AMODE, int OUTBF, int VT>
__global__ __launch_bounds__(64, 2) void k_gemm_w(
    const void* __restrict__ A, const void* __restrict__ W, long woff,
    const void* __restrict__ bias, long boff, const int* __restrict__ flb,
    const float* __restrict__ res, void* __restrict__ C,
    int N, const int* __restrict__ fl,
    const unsigned short* __restrict__ mop, const float* __restrict__ mml,
    bf16* __restrict__ vtout,
    const void* __restrict__ lnw, long lnwoff,
    const void* __restrict__ lnb, long lnboff) {
  constexpr int NK = KT / 32;
  int isb = *fl;
  int ln = threadIdx.x;
  int quad = ln >> 4, l16 = ln & 15;
  int m0 = blockIdx.y * 16, n0 = blockIdx.x * (16 * NTW);
  __shared__ unsigned short Als[(AMODE >= 2) ? 16 : 1][200];
  if constexpr (AMODE == 3) {
    // fused LayerNorm over K=192: 4 lanes/row, 48 contiguous elems each
    int row = ln >> 2, j = ln & 3;
    const float* xr = (const float*)A + (long)(m0 + row) * 192 + j * 48;
    float av[48];
#pragma unroll
    for (int q = 0; q < 12; ++q) {
      float4 v = *(const float4*)(xr + q * 4);
      av[q * 4 + 0] = v.x; av[q * 4 + 1] = v.y;
      av[q * 4 + 2] = v.z; av[q * 4 + 3] = v.w;
    }
    float sum = 0.0f;
#pragma unroll
    for (int q = 0; q < 48; ++q) sum += av[q];
    sum += __shfl_xor(sum, 1);
    sum += __shfl_xor(sum, 2);
    float mean = sum * (1.0f / 192.0f);
    float vs = 0.0f;
#pragma unroll
    for (int q = 0; q < 48; ++q) { float d = av[q] - mean; vs += d * d; }
    vs += __shfl_xor(vs, 1);
    vs += __shfl_xor(vs, 2);
    float rstd = rsqrtf(vs * (1.0f / 192.0f) + 1e-5f);
#pragma unroll
    for (int g = 0; g < 6; ++g) {
      union { unsigned short u[8]; uint4 v; } pk;
#pragma unroll
      for (int e = 0; e < 8; ++e) {
        long k = j * 48 + g * 8 + e;
        float gg = ldw(lnw, lnwoff + k, isb);
        float bb = ldw(lnb, lnboff + k, isb);
        pk.u[e] = bfr((av[g * 8 + e] - mean) * rstd * gg + bb);
      }
      *(uint4*)&Als[row][j * 48 + g * 8] = pk.v;
    }
  } else if constexpr (AMODE == 2) {
    // fused attention merge: 4 lanes/row; lane j covers head j's 48 dims exactly
    int row = ln >> 2, j = ln & 3;
    int m = m0 + row;
    int rr = m & 1023, bb = m >> 10;
    long idx[4];
    float ms[4], ls[4];
    float Ms = -1e30f;
#pragma unroll
    for (int s = 0; s < 4; ++s) {
      idx[s] = (((long)s * 2 + bb) * 4 + j) * 1024 + rr;
      ms[s] = mml[idx[s] * 2];
      ls[s] = mml[idx[s] * 2 + 1];
      Ms = fmaxf(Ms, ms[s]);
    }
    float e4[4], L = 0.0f;
#pragma unroll
    for (int s = 0; s < 4; ++s) { e4[s] = __expf(ms[s] - Ms); L += ls[s] * e4[s]; }
    float invL = 1.0f / L;
#pragma unroll
    for (int g = 0; g < 6; ++g) {
      union { unsigned short u[8]; uint4 v; } pk;
#pragma unroll
      for (int e2 = 0; e2 < 8; ++e2) {
        float o = 0.0f;
#pragma unroll
        for (int s = 0; s < 4; ++s) o += shf(mop[idx[s] * 48 + g * 8 + e2]) * e4[s];
        pk.u[e2] = bfr(o * invL);
      }
      *(uint4*)&Als[row][j * 48 + g * 8] = pk.v;
    }
  }
  f32x4 acc[NTW] = {};
  auto lda = [&](int kc) -> bf16x8 {
    if constexpr (AMODE >= 2) {
      return *(const bf16x8*)&Als[l16][kc * 32 + quad * 8];
    } else if constexpr (AMODE == 1) {
      return *(const bf16x8*)((const unsigned short*)A + (long)(m0 + l16) * KT + kc * 32 + quad * 8);
    } else {
      const float* ap = (const float*)A + (long)(m0 + l16) * KT + kc * 32 + quad * 8;
      float4 a0 = *(const float4*)ap;
      float4 a1 = *(const float4*)(ap + 4);
      union { unsigned short u[8]; bf16x8 v; } pk;
      pk.u[0] = bfr(a0.x); pk.u[1] = bfr(a0.y); pk.u[2] = bfr(a0.z); pk.u[3] = bfr(a0.w);
      pk.u[4] = bfr(a1.x); pk.u[5] = bfr(a1.y); pk.u[6] = bfr(a1.z); pk.u[7] = bfr(a1.w);
      return pk.v;
    }
  };
  if (isb) {
    const unsigned short* wb = (const unsigned short*)W + woff + (long)l16 * KT + quad * 8;
    for (int kc = 0; kc < NK; ++kc) {
      bf16x8 af = lda(kc);
#pragma unroll
      for (int nt = 0; nt < NTW; ++nt) {
        bf16x8 wf = *(const bf16x8*)(wb + (long)(n0 + nt * 16) * KT + kc * 32);
        acc[nt] = __builtin_amdgcn_mfma_f32_16x16x32_bf16(af, wf, acc[nt], 0, 0, 0);
      }
    }
  } else {
    const float* wb = (const float*)W + woff + (long)l16 * KT + quad * 8;
    for (int kc = 0; kc < NK; ++kc) {
      bf16x8 af = lda(kc);
#pragma unroll
      for (int nt = 0; nt < NTW; ++nt) {
        const float* wp = wb + (long)(n0 + nt * 16) * KT + kc * 32;
        float4 w0 = *(const float4*)wp;
        float4 w1 = *(const float4*)(wp + 4);
        union { unsigned short u[8]; bf16x8 v; } pk;
        pk.u[0] = bfr(w0.x); pk.u[1] = bfr(w0.y); pk.u[2] = bfr(w0.z); pk.u[3] = bfr(w0.w);
        pk.u[4] = bfr(w1.x); pk.u[5] = bfr(w1.y); pk.u[6] = bfr(w1.z); pk.u[7] = bfr(w1.w);
        acc[nt] = __builtin_amdgcn_mfma_f32_16x16x32_bf16(af, pk.v, acc[nt], 0, 0, 0);
      }
    }
  }
  int isbb = *flb;
#pragma unroll
  for (int nt = 0; nt < NTW; ++nt) {
    int n = n0 + nt * 16 + l16;
    float bv = ldw(bias, boff + n, isbb);
#pragma unroll
    for (int r = 0; r < 4; ++r) {
      int m = m0 + quad * 4 + r;
      float v = acc[nt][r] + bv;
      if (HASRES) v += res[(long)m * N + n];
      if (ACT == 1) v = gelu_exact(v);
      if (OUTBF) ((bf16*)C)[(long)m * N + n] = f2bf(v);
      else ((float*)C)[(long)m * N + n] = v;
      if constexpr (VT) {
        if (n >= 384) {
          int hh = (n - 384) / 48, dd = (n - 384) % 48;
          int row = m & 1023, bb = m >> 10;
          vtout[((long)(bb * 4 + hh) * 48 + dd) * 1024 + row] = f2bf(v);
        }
      }
    }
  }
}

// ---------------- head second layer: wave-per-output dot (N=2, K=192) ----------------
__global__ __launch_bounds__(256) void k_head2(const float* __restrict__ A,
                                               const void* __restrict__ W,
                                               const void* __restrict__ bias,
                                               float* __restrict__ C,
                                               const int* __restrict__ fl) {
  int isb = *fl;
  int wv = threadIdx.x >> 6, ln = threadIdx.x & 63;
  int gw = blockIdx.x * 4 + wv;  // 0..4095
  int m = gw >> 1, n = gw & 1;
  const float* a = A + (long)m * 192;
  float s = 0.0f;
#pragma unroll
  for (int q = 0; q < 3; ++q) {
    int j = ln + q * 64;
    s += a[j] * ldw(W, (long)n * 192 + j, isb);
  }
  for (int o = 32; o; o >>= 1) s += __shfl_xor(s, o);
  if (ln == 0) {
    int b = m >> 10, p = m & 1023;
    C[((long)b * 2 + n) * 1024 + p] = s + ldw(bias, n, isb);
  }
}

// ---------------- MFMA flash attention, split-K (4 splits of 4 chunks) -------------------
__global__ __launch_bounds__(256) void k_attn_mfma(const bf16* __restrict__ qkv,
                                                   const bf16* __restrict__ vt,
                                                   unsigned short* __restrict__ opart,
                                                   float* __restrict__ ml) {
  __shared__ unsigned short Qs[64][72];
  __shared__ unsigned short Ks[64][72];
  __shared__ unsigned short Vs[48][72];
  __shared__ unsigned short Ps[64][72];
  int tid = threadIdx.x;
  int wv = tid >> 6, ln = tid & 63, quad = ln >> 4, l16 = ln & 15;
  int h = blockIdx.y, b = blockIdx.z;
  int qt = blockIdx.x >> 2, s = blockIdx.x & 3;
  int q0 = qt * 64;
  const unsigned short* qp = (const unsigned short*)qkv + (long)b * 1024 * 576;
  const unsigned short* vp = (const unsigned short*)vt + ((long)(b * 4 + h) * 48) * 1024;
  for (int i = tid; i < 384; i += 256) {
    int r = i / 6, c = i % 6;
    *(uint4*)&Qs[r][c * 8] = *(const uint4*)(qp + (long)(q0 + r) * 576 + h * 48 + c * 8);
  }
  for (int i = tid; i < 128; i += 256) {
    int r = i >> 1, c = 6 + (i & 1);
    uint4 z = {0, 0, 0, 0};
    *(uint4*)&Qs[r][c * 8] = z;
  }
  float m[4] = {-1e30f, -1e30f, -1e30f, -1e30f};
  float l[4] = {0.0f, 0.0f, 0.0f, 0.0f};
  f32x4 accO[3] = {};
  const float SC = 0.14433756729740643f;
  for (int kc = s * 4; kc < s * 4 + 4; ++kc) {
    int k0 = kc * 64;
    for (int i = tid; i < 384; i += 256) {
      int r = i / 6, c = i % 6;
      *(uint4*)&Ks[r][c * 8] = *(const uint4*)(qp + (long)(k0 + r) * 576 + 192 + h * 48 + c * 8);
    }
    for (int i = tid; i < 128; i += 256) {
      int r = i >> 1, c = 6 + (i & 1);
      uint4 z = {0, 0, 0, 0};
      *(uint4*)&Ks[r][c * 8] = z;
    }
    for (int i = tid; i < 384; i += 256) {
      int d = i >> 3, c = i & 7;
      *(uint4*)&Vs[d][c * 8] = *(const uint4*)(vp + (long)d * 1024 + k0 + c * 8);
    }
    __syncthreads();
    f32x4 accS[4] = {};
    bf16x8 a0 = *(const bf16x8*)&Qs[wv * 16 + l16][quad * 8];
    bf16x8 a1 = *(const bf16x8*)&Qs[wv * 16 + l16][32 + quad * 8];
#pragma unroll
    for (int ct = 0; ct < 4; ++ct) {
      bf16x8 b0 = *(const bf16x8*)&Ks[ct * 16 + l16][quad * 8];
      bf16x8 b1 = *(const bf16x8*)&Ks[ct * 16 + l16][32 + quad * 8];
      accS[ct] = __builtin_amdgcn_mfma_f32_16x16x32_bf16(a0, b0, accS[ct], 0, 0, 0);
      accS[ct] = __builtin_amdgcn_mfma_f32_16x16x32_bf16(a1, b1, accS[ct], 0, 0, 0);
    }
#pragma unroll
    for (int r = 0; r < 4; ++r) {
      float s0 = accS[0][r] * SC, s1 = accS[1][r] * SC;
      float s2 = accS[2][r] * SC, s3 = accS[3][r] * SC;
      float mx = fmaxf(fmaxf(s0, s1), fmaxf(s2, s3));
      for (int o = 8; o; o >>= 1) mx = fmaxf(mx, __shfl_xor(mx, o));
      float mn = fmaxf(m[r], mx);
      float alpha = __expf(m[r] - mn);
      float p0 = __expf(s0 - mn), p1 = __expf(s1 - mn);
      float p2 = __expf(s2 - mn), p3 = __expf(s3 - mn);
      float rs = p0 + p1 + p2 + p3;
      for (int o = 8; o; o >>= 1) rs += __shfl_xor(rs, o);
      m[r] = mn;
      l[r] = l[r] * alpha + rs;
      accO[0][r] *= alpha; accO[1][r] *= alpha; accO[2][r] *= alpha;
      int prow = wv * 16 + quad * 4 + r;
      Ps[prow][l16]      = bfr(p0);
      Ps[prow][16 + l16] = bfr(p1);
      Ps[prow][32 + l16] = bfr(p2);
      Ps[prow][48 + l16] = bfr(p3);
    }
    bf16x8 pf0 = *(const bf16x8*)&Ps[wv * 16 + l16][quad * 8];
    bf16x8 pf1 = *(const bf16x8*)&Ps[wv * 16 + l16][32 + quad * 8];
#pragma unroll
    for (int ct = 0; ct < 3; ++ct) {
      bf16x8 v0 = *(const bf16x8*)&Vs[ct * 16 + l16][quad * 8];
      bf16x8 v1 = *(const bf16x8*)&Vs[ct * 16 + l16][32 + quad * 8];
      accO[ct] = __builtin_amdgcn_mfma_f32_16x16x32_bf16(pf0, v0, accO[ct], 0, 0, 0);
      accO[ct] = __builtin_amdgcn_mfma_f32_16x16x32_bf16(pf1, v1, accO[ct], 0, 0, 0);
    }
    __syncthreads();
  }
  long base = (((long)s * 2 + b) * 4 + h) * 1024;
#pragma unroll
  for (int r = 0; r < 4; ++r) {
    int row = q0 + wv * 16 + quad * 4 + r;
#pragma unroll
    for (int ct = 0; ct < 3; ++ct)
      opart[(base + row) * 48 + ct * 16 + l16] = bfr(accO[ct][r]);
    if (l16 == 0) {
      ml[(base + row) * 2]     = m[r];
      ml[(base + row) * 2 + 1] = l[r];
    }
  }
}

// ---------------- EMA ----------------
__global__ void k_ema(float* __restrict__ x) {
  int i = blockIdx.x * blockDim.x + threadIdx.x;
  if (i < 196608) x[196608 + i] = 0.8f * x[196608 + i] + 0.2f * x[i];
}

extern "C" void kernel_launch(void* const* d_in, const int* in_sizes, int n_in,
                              void* d_out, int out_size, void* d_ws, size_t ws_size,
                              hipStream_t stream) {
  const void* feats_l1 = d_in[0];
  const void* feats_l2 = d_in[1];
  const void* tok_w = d_in[3];
  const void* tok_b = d_in[4];
  const void* lcm_ln1_w = d_in[5];
  const void* lcm_ln1_b = d_in[6];
  const void* lcm_in_w  = d_in[7];
  const void* lcm_in_b  = d_in[8];
  const void* lcm_out_w = d_in[9];
  const void* lcm_out_b = d_in[10];
  const void* lcm_ln2_w = d_in[11];
  const void* lcm_ln2_b = d_in[12];
  const void* lcm_mlp_w1 = d_in[13];
  const void* lcm_mlp_b1 = d_in[14];
  const void* lcm_mlp_w2 = d_in[15];
  const void* lcm_mlp_b2 = d_in[16];
  const void* gtr_ln1_w = d_in[17];
  const void* gtr_ln1_b = d_in[18];
  const void* gtr_in_w  = d_in[19];
  const void* gtr_in_b  = d_in[20];
  const void* gtr_out_w = d_in[21];
  const void* gtr_out_b = d_in[22];
  const void* gtr_ln2_w = d_in[23];
  const void* gtr_ln2_b = d_in[24];
  const void* gtr_mlp_w1 = d_in[25];
  const void* gtr_mlp_b1 = d_in[26];
  const void* gtr_mlp_w2 = d_in[27];
  const void* gtr_mlp_b2 = d_in[28];
  const void* head_w1 = d_in[29];
  const void* head_b1 = d_in[30];
  const void* head_w2 = d_in[31];
  const void* head_b2 = d_in[32];
  const void* ref1_w1 = d_in[33];
  const void* ref1_b1 = d_in[34];
  const void* ref1_w2 = d_in[35];
  const void* ref1_b2 = d_in[36];
  const void* ref0_w1 = d_in[37];
  const void* ref0_b1 = d_in[38];
  const void* ref0_w2 = d_in[39];
  const void* ref0_b2 = d_in[40];
  (void)ws_size; (void)n_in; (void)in_sizes; (void)out_size;

  // ---- workspace layout (f-eq units; ~16.8 MB) ----
  int* flag = (int*)d_ws;
  int* oneflag = (int*)d_ws + 2;
  float* wsf = (float*)d_ws;
  float* F2   = wsf + 16;             // 393216 (spare)
  float* rA   = F2 + 393216;          // 786432 : opart bf16
  float* rX   = rA + 786432;          // 393216 : residual x
  float* rT   = rX + 393216;          // 393216 : head-hidden | mid0packed
  float* rY   = rT + 393216;          // 393216 : mlbuf | mid1packed
  float* big  = rY + 393216;          // 1572864: qkv/vt/hid [0,851968) | Fp2+Fp1 tail
  float* fv   = big + 1572864;        // 4096 (unused)
  float* cur  = fv + 4096;            // 4096
  float* cur2 = cur + 4096;           // 16384
  float* cb1a = cur2 + 16384;         // 128
  float* cb1b = cb1a + 128;           // 16
  float* cb0a = cb1b + 16;            // 64
  float* cb0b = cb0a + 64;            // 16
  bf16* wtok  = (bf16*)(cb0b + 16);   // 12288 shorts
  float* wpk  = cb0b + 16 + 6144;
  bf16* w1p1 = (bf16*)wpk;            // 331776 shorts
  bf16* w1p2 = (bf16*)(wpk + 165888); // 18432 shorts
  bf16* w0p1 = (bf16*)(wpk + 175104); // 92160 shorts
  bf16* w0p2 = (bf16*)(wpk + 221184); // 9216 shorts

  float* x = rX;
  bf16* corrTb = (bf16*)big;
  bf16* qkvbb  = (bf16*)big;
  bf16* vtb    = (bf16*)(big + 655360);
  bf16* hidb   = (bf16*)big;
  unsigned short* opart = (unsigned short*)rA;  // [4][2][4][1024][48] bf16
  float* mlbuf = rY;                            // [4][2][4][1024][2] fp32
  float* headh = rT;
  bf16* mid0p = (bf16*)rT;
  bf16* mid1p = (bf16*)rY;
  bf16* Fp2   = (bf16*)(big + 851968);   // [3][1024][128]
  bf16* Fp1   = (bf16*)(big + 1048576);  // [3][4096][64]

  k_detect<<<1, 256, 0, stream>>>((const unsigned short*)feats_l1, flag);
  k_setone<<<1, 1, 0, stream>>>(oneflag);
  k_cvt<<<1, 256, 0, stream>>>(ref1_b1, cb1a, 128, flag);
  k_cvt<<<1, 256, 0, stream>>>(ref1_b2, cb1b, 2, flag);
  k_cvt<<<1, 256, 0, stream>>>(ref0_b1, cb0a, 64, flag);
  k_cvt<<<1, 256, 0, stream>>>(ref0_b2, cb0b, 2, flag);
  k_padtokw<<<48, 256, 0, stream>>>(tok_w, wtok, flag);
  k_packw<<<1296, 256, 0, stream>>>(ref1_w1, w1p1, 128, 128, 258, 128, 288, 331776, flag);
  k_packw<<<72, 256, 0, stream>>>(ref1_w2, w1p2, 2, 128, 128, 16, 128, 18432, flag);
  k_packw<<<360, 256, 0, stream>>>(ref0_w1, w0p1, 64, 64, 130, 64, 160, 92160, flag);
  k_packw<<<36, 256, 0, stream>>>(ref0_w2, w0p2, 2, 64, 64, 16, 64, 9216, flag);
  // pixel-major frames up front (big tail survives qkv/hid which use [0,851968))
  k_trans_feats<<<192, 256, 0, stream>>>(feats_l2, Fp2, 3, 128, 1024, flag);
  k_trans_feats<<<384, 256, 0, stream>>>(feats_l1, Fp1, 3, 64, 4096, flag);

  // ---- tokens: corr (from Fp2) then tokenizer GEMM (wave-GEMM) ----
  k_corr<<<dim3(1024, 2), 64, 0, stream>>>(Fp2, corrTb);
  k_gemm_w<64, 4, 0, false, 1, 0, 0><<<dim3(3, 128), 64, 0, stream>>>(
      corrTb, wtok, 0, tok_b, 192, flag, nullptr, x, 192, oneflag,
      nullptr, nullptr, nullptr, nullptr, 0, nullptr, 0);

  auto run_block = [&](const void* ln1w, long o1, const void* ln1b, long o2,
                       const void* inw, long o3, const void* inb, long o4,
                       const void* ow, long o5, const void* ob, long o6,
                       const void* ln2w, long o7, const void* ln2b, long o8,
                       const void* w1, long o9, const void* b1, long o10,
                       const void* w2, long o11, const void* b2, long o12) {
    // fused LN1 + qkv GEMM: bf16 out + fused V-transpose scatter
    k_gemm_w<192, 4, 0, false, 3, 1, 1><<<dim3(9, 128), 64, 0, stream>>>(
        x, inw, o3, inb, o4, flag, nullptr, qkvbb, 576, flag,
        nullptr, nullptr, vtb, ln1w, o1, ln1b, o2);
    k_attn_mfma<<<dim3(64, 4, 2), 256, 0, stream>>>(qkvbb, vtb, opart, mlbuf);
    // out-proj GEMM: fused 4-way split-K merge as A-operand
    k_gemm_w<192, 4, 0, true, 2, 0, 0><<<dim3(3, 128), 64, 0, stream>>>(
        nullptr, ow, o5, ob, o6, flag, x, x, 192, flag,
        opart, mlbuf, nullptr, nullptr, 0, nullptr, 0);
    // fused LN2 + mlp1 GEMM
    k_gemm_w<192, 4, 1, false, 3, 1, 0><<<dim3(12, 128), 64, 0, stream>>>(
        x, w1, o9, b1, o10, flag, nullptr, hidb, 768, flag,
        nullptr, nullptr, nullptr, ln2w, o7, ln2b, o8);
    // mlp2 (K=768)
    k_gemm_w<768, 4, 0, true, 1, 0, 0><<<dim3(3, 128), 64, 0, stream>>>(
        hidb, w2, o11, b2, o12, flag, x, x, 192, flag,
        nullptr, nullptr, nullptr, nullptr, 0, nullptr, 0);
  };

  for (int i = 0; i < 6; ++i) {
    run_block(lcm_ln1_w, (long)i * 192, lcm_ln1_b, (long)i * 192,
              lcm_in_w, (long)i * 110592, lcm_in_b, (long)i * 576,
              lcm_out_w, (long)i * 36864, lcm_out_b, (long)i * 192,
              lcm_ln2_w, (long)i * 192, lcm_ln2_b, (long)i * 192,
              lcm_mlp_w1, (long)i * 147456, lcm_mlp_b1, (long)i * 768,
              lcm_mlp_w2, (long)i * 147456, lcm_mlp_b2, (long)i * 192);
  }
  k_ema<<<768, 256, 0, stream>>>(x);

  for (int i = 0; i < 2; ++i) {
    run_block(gtr_ln1_w, (long)i * 192, gtr_ln1_b, (long)i * 192,
              gtr_in_w, (long)i * 110592, gtr_in_b, (long)i * 576,
              gtr_out_w, (long)i * 36864, gtr_out_b, (long)i * 192,
              gtr_ln2_w, (long)i * 192, gtr_ln2_b, (long)i * 192,
              gtr_mlp_w1, (long)i * 147456, gtr_mlp_b1, (long)i * 768,
              gtr_mlp_w2, (long)i * 147456, gtr_mlp_b2, (long)i * 192);
  }

  // ---- head -> coarse flow (wave-dot second layer writes [b][2][1024]) ----
  k_gemm_w<192, 4, 1, false, 0, 0, 0><<<dim3(3, 128), 64, 0, stream>>>(
      x, head_w1, 0, head_b1, 0, flag, nullptr, headh, 192, flag,
      nullptr, nullptr, nullptr, nullptr, 0, nullptr, 0);
  k_head2<<<1024, 256, 0, stream>>>(headh, head_w2, head_b2, cur, flag);

  // ---- decoder prep: zero mid buffers (borders must stay 0) ----
  k_zerosh<<<768, 256, 0, stream>>>((unsigned short*)rT, 196608);

  // ---- decoder level 1 (32x32): C=128, ICP=288, OC=128 ----
  for (int it = 0; it < 4; ++it) {
    k_conv1d<128, 288, 128, 32, 5, 0><<<dim3(8, 64, 2), 64, 0, stream>>>(
        Fp2, cur, w1p1, cb1a, mid1p);
    k_conv2_dot<128, 32, 5, 0, 0><<<512, 256, 0, stream>>>(
        mid1p, w1p2, cb1b, cur, nullptr, nullptr, nullptr);
  }

  // ---- decoder level 0 (64x64): C=64, ICP=160, OC=64; upsample folded into it=0,
  //      final output write folded into it=3 ----
  k_conv1d<64, 160, 64, 64, 6, 1><<<dim3(4, 256, 2), 64, 0, stream>>>(
      Fp1, cur, w0p1, cb0a, mid0p);
  k_conv2_dot<64, 64, 6, 1, 0><<<2048, 256, 0, stream>>>(
      mid0p, w0p2, cb0b, cur2, cur, nullptr, nullptr);
  for (int it = 1; it < 3; ++it) {
    k_conv1d<64, 160, 64, 64, 6, 0><<<dim3(4, 256, 2), 64, 0, stream>>>(
        Fp1, cur2, w0p1, cb0a, mid0p);
    k_conv2_dot<64, 64, 6, 0, 0><<<2048, 256, 0, stream>>>(
        mid0p, w0p2, cb0b, cur2, nullptr, nullptr, nullptr);
  }
  k_conv1d<64, 160, 64, 64, 6, 0><<<dim3(4, 256, 2), 64, 0, stream>>>(
      Fp1, cur2, w0p1, cb0a, mid0p);
  k_conv2_dot<64, 64, 6, 0, 1><<<2048, 256, 0, stream>>>(
      mid0p, w0p2, cb0b, cur2, nullptr, d_out, flag);
}